// Round 14
// baseline (273.188 us; speedup 1.0000x reference)
//
#include <hip/hip_runtime.h>

typedef unsigned short u16;
typedef unsigned int   u32;
typedef __attribute__((ext_vector_type(8))) short bf16x8;
typedef __attribute__((ext_vector_type(4))) float f32x4;

#define EPSc 1e-5f
#define INFc 1e5f

// ---------------- ws byte offsets ----------------
#define O_LINJ  0         // f32[1024][64]
#define O_LINI  262144    // f32[1024][64]
#define O_VSC   524288    // f32[1024]
#define O_WE2F  528384    // u16[4*2*64*8]  (cols permuted: c = 4*l15+n)
#define O_WC1F  536576    // u16[5*2*64*8]  (n<4 permuted; tile4 = Ws|0)
#define O_WC2F  546816    // u16[2*2*64*8]  (natural)
#define O_WP1C  550912    // f32[32][64]
#define O_WP2C  559104    // f32[64][64]
#define O_WN2C  575488    // f32[64][64]
#define O_WN1C  591872    // f32[384][64]
#define O_XF    690176    // f32[1024*3]
#define O_VF    702464    // f32[1024*3]
#define O_BIAS  714752    // f32[552]
#define O_SYNC  741568    // u32 order | u32 done  (memset to 0 each launch)

// biasf float indices
#define B_BE2 0
#define B_BC1 64
#define B_BC2 128
#define B_BS  160
#define B_GE  164
#define B_BP1 168
#define B_BP2 232
#define B_BN1 296
#define B_BN2 360
#define B_W1L 424
#define B_BE1 488

#define NPREP 22

struct P {
    const void *h, *x, *v;
    const void *We1, *be1, *We2, *be2, *Wc1, *bc1, *Wc2, *bc2;
    const void *Wp1, *bp1, *Wp2, *bp2, *Ws_, *bs_;
    const void *Wn1, *bn1, *Wn2, *bn2, *Wv1, *bv1, *Wv2, *lg;
    float *linj, *lini, *vsc, *wp1c, *wp2c, *wn1c, *wn2c, *xf, *vf, *biasf;
    u16 *we2f, *wc1f, *wc2f;
    u32 *order, *done;
    void *out;
};

__device__ __forceinline__ float bfr(u16 u) { return __uint_as_float(((u32)u) << 16); }
__device__ __forceinline__ u16 f2bf(float f) {
    u32 u = __float_as_uint(f);
    u = u + 0x7fffu + ((u >> 16) & 1u);
    return (u16)(u >> 16);
}
__device__ __forceinline__ u32 cvtpk(float lo, float hi) {
    u32 r;
    asm("v_cvt_pk_bf16_f32 %0, %1, %2" : "=v"(r) : "v"(lo), "v"(hi));
    return r;
}
__device__ __forceinline__ float frcp(float x) { return __builtin_amdgcn_rcpf(x); }
__device__ __forceinline__ float silu(float x) { return x * frcp(1.f + __expf(-x)); }
__device__ __forceinline__ float lrelu(float x) { return x > 0.f ? x : 0.2f * x; }

__device__ __forceinline__ float LDr(const void* p, int i, bool bf) {
    return bf ? bfr(((const u16*)p)[i]) : ((const float*)p)[i];
}
__device__ __forceinline__ u16 ENCr(const void* p, int i, bool bf) {
    return bf ? ((const u16*)p)[i] : f2bf(((const float*)p)[i]);
}
__device__ __forceinline__ void STr(void* p, int i, float v, bool bf) {
    if (bf) ((u16*)p)[i] = (u16)cvtpk(v, v);
    else    ((float*)p)[i] = v;
}
#define WAVE_FENCE() do { asm volatile("s_waitcnt lgkmcnt(0)" ::: "memory"); \
                          __builtin_amdgcn_sched_barrier(0); } while (0)

// per-block inline dtype detect (pure function of h)
__device__ __forceinline__ bool block_flag(const void* h, u32* s_flagv, int t) {
    if (t < 64) {
        const u16* ph = (const u16*)h;
        int cnt = 0;
        #pragma unroll
        for (int e = 0; e < 4; e++) {
            float v = bfr(ph[t * 4 + e]);
            float a = fabsf(v);
            if (v == 0.f || (a > 1e-6f && a < 1024.f)) cnt++;
        }
        #pragma unroll
        for (int o = 32; o; o >>= 1) cnt += __shfl_xor(cnt, o);
        if (t == 0) *s_flagv = (cnt >= 224) ? 1u : 0u;
    }
    __syncthreads();
    return *s_flagv != 0u;
}

// ---------------- prep slice (tk = 0..21); scratch aliases s_A (>=33,792 B) ----------------
__device__ void prep_slice(int tk, const P& p, bool bf, int t, u16* scratch) {
    if (tk == 0) {
        for (int idx = t; idx < 4096; idx += 256) {
            int e = idx & 7, l = (idx >> 3) & 63, ks = (idx >> 9) & 1, nt = idx >> 10;
            int k = ks * 32 + (l >> 4) * 8 + e, c = (l & 15) * 4 + nt;
            p.we2f[idx] = ENCr(p.We2, k * 64 + c, bf);
        }
    } else if (tk == 1) {
        for (int idx = t; idx < 5120; idx += 256) {
            int e = idx & 7, l = (idx >> 3) & 63, ks = (idx >> 9) & 1, nt = idx >> 10;
            int k = ks * 32 + (l >> 4) * 8 + e;
            u16 v;
            if (nt < 4) v = ENCr(p.Wc1, k * 64 + (l & 15) * 4 + nt, bf);
            else { int cc = l & 15; v = (cc < 4) ? ENCr(p.Ws_, k * 4 + cc, bf) : (u16)0; }
            p.wc1f[idx] = v;
        }
    } else if (tk == 2) {
        for (int idx = t; idx < 2048; idx += 256) {
            int e = idx & 7, l = (idx >> 3) & 63, ks = (idx >> 9) & 1, nt = idx >> 10;
            int k = ks * 32 + (l >> 4) * 8 + e, c = nt * 16 + (l & 15);
            p.wc2f[idx] = ENCr(p.Wc2, k * 32 + c, bf);
        }
        if (t < 64) {
            p.biasf[B_BE2 + t] = LDr(p.be2, t, bf);
            p.biasf[B_BC1 + t] = LDr(p.bc1, t, bf);
            p.biasf[B_BP1 + t] = LDr(p.bp1, t, bf);
            p.biasf[B_BP2 + t] = LDr(p.bp2, t, bf);
            p.biasf[B_BN1 + t] = LDr(p.bn1, t, bf);
            p.biasf[B_BN2 + t] = LDr(p.bn2, t, bf);
            p.biasf[B_W1L + t] = LDr(p.We1, 128 * 64 + t, bf);
            p.biasf[B_BE1 + t] = LDr(p.be1, t, bf);
        } else if (t < 96) {
            p.biasf[B_BC2 + (t - 64)] = LDr(p.bc2, t - 64, bf);
        } else if (t < 100) {
            p.biasf[B_BS + (t - 96)] = LDr(p.bs_, t - 96, bf);
            p.biasf[B_GE + (t - 96)] = __expf(LDr(p.lg, t - 96, bf));
        }
        for (int i2 = t; i2 < 3072; i2 += 256) {
            p.xf[i2] = LDr(p.x, i2, bf);
            p.vf[i2] = LDr(p.v, i2, bf);
        }
    } else if (tk == 3) {
        for (int idx = t; idx < 2048; idx += 256) p.wp1c[idx] = LDr(p.Wp1, idx, bf);
        for (int idx = t; idx < 4096; idx += 256) p.wp2c[idx] = LDr(p.Wp2, idx, bf);
        for (int idx = t; idx < 4096; idx += 256) p.wn2c[idx] = LDr(p.Wn2, idx, bf);
    } else if (tk == 4) {
        for (int idx = t; idx < 12288; idx += 256) p.wn1c[idx] = LDr(p.Wn1, idx, bf);
    } else if (tk == 5) {
        for (int idx = t; idx < 12288; idx += 256) p.wn1c[12288 + idx] = LDr(p.Wn1, 12288 + idx, bf);
    } else {
        // node slices: 4 waves x 16 nodes; weights staged in aliased LDS
        u16* lds_wj = scratch;            // [4096]
        u16* lds_wi = scratch + 4096;     // [4096]
        u16* lds_wv = scratch + 8192;     // [4096]
        u16* shh    = scratch + 12288;    // [4][16*72]
        for (int idx = t; idx < 4096; idx += 256) {
            lds_wj[idx] = ENCr(p.We1, idx, bf);
            lds_wi[idx] = ENCr(p.We1, 4096 + idx, bf);
            lds_wv[idx] = ENCr(p.Wv1, idx, bf);
        }
        const int w = t >> 6, lane = t & 63;
        const int l15 = lane & 15, l4 = lane >> 4;
        const int n0 = (tk - 6) * 64 + w * 16;
        u16* myh = shh + w * (16 * 72);
        #pragma unroll
        for (int rr = 0; rr < 4; rr++) {
            int row = rr * 4 + l4;
            if (bf) {
                const u16* hb = (const u16*)p.h;
                *(uint2*)(&myh[row * 72 + l15 * 4]) =
                    *(const uint2*)(&hb[(n0 + row) * 64 + l15 * 4]);
            } else {
                const float* hf = (const float*)p.h;
                f32x4 hv = *(const f32x4*)(&hf[(n0 + row) * 64 + l15 * 4]);
                uint2 ww; ww.x = cvtpk(hv[0], hv[1]); ww.y = cvtpk(hv[2], hv[3]);
                *(uint2*)(&myh[row * 72 + l15 * 4]) = ww;
            }
        }
        __syncthreads();
        f32x4 dj[4] = {}, di[4] = {}, dv[4] = {};
        #pragma unroll
        for (int nt = 0; nt < 4; nt++) {
            #pragma unroll
            for (int ks = 0; ks < 2; ks++) {
                bf16x8 a = *(const bf16x8*)(&myh[l15 * 72 + ks * 32 + l4 * 8]);
                bf16x8 bj, bi2, bvv;
                #pragma unroll
                for (int e = 0; e < 8; e++) {
                    int off = (ks * 32 + l4 * 8 + e) * 64 + nt * 16 + l15;
                    bj[e]  = (short)lds_wj[off];
                    bi2[e] = (short)lds_wi[off];
                    bvv[e] = (short)lds_wv[off];
                }
                dj[nt] = __builtin_amdgcn_mfma_f32_16x16x32_bf16(a, bj,  dj[nt], 0, 0, 0);
                di[nt] = __builtin_amdgcn_mfma_f32_16x16x32_bf16(a, bi2, di[nt], 0, 0, 0);
                dv[nt] = __builtin_amdgcn_mfma_f32_16x16x32_bf16(a, bvv, dv[nt], 0, 0, 0);
            }
        }
        #pragma unroll
        for (int nt = 0; nt < 4; nt++)
            #pragma unroll
            for (int q = 0; q < 4; q++) {
                int n = n0 + l4 * 4 + q, c = nt * 16 + l15;
                p.linj[n * 64 + c] = dj[nt][q];
                p.lini[n * 64 + c] = di[nt][q];
            }
        float bv1v[4], wv2v[4];
        #pragma unroll
        for (int nt = 0; nt < 4; nt++) {
            bv1v[nt] = LDr(p.bv1, nt * 16 + l15, bf);
            wv2v[nt] = LDr(p.Wv2, nt * 16 + l15, bf);
        }
        #pragma unroll
        for (int q = 0; q < 4; q++) {
            float s = 0.f;
            #pragma unroll
            for (int nt = 0; nt < 4; nt++)
                s += silu(dv[nt][q] + bv1v[nt]) * wv2v[nt];
            s += __shfl_xor(s, 1);
            s += __shfl_xor(s, 2);
            s += __shfl_xor(s, 4);
            s += __shfl_xor(s, 8);
            if (l15 == 0) p.vsc[n0 + l4 * 4 + q] = s;
        }
    }
}

// N-channel block reduction, 256 threads
template<int N>
__device__ __forceinline__ void blk_red(float v[N], bool domax, float* scr, int tid) {
    #pragma unroll
    for (int s2 = 32; s2; s2 >>= 1)
        #pragma unroll
        for (int u = 0; u < N; u++) {
            float o = __shfl_xor(v[u], s2);
            v[u] = domax ? fmaxf(v[u], o) : (v[u] + o);
        }
    if ((tid & 63) == 0) {
        int w = tid >> 6;
        #pragma unroll
        for (int u = 0; u < N; u++) scr[w * N + u] = v[u];
    }
    __syncthreads();
    #pragma unroll
    for (int u = 0; u < N; u++) {
        float a = scr[0 * N + u], b2 = scr[1 * N + u], c = scr[2 * N + u], d = scr[3 * N + u];
        v[u] = domax ? fmaxf(fmaxf(a, b2), fmaxf(c, d)) : ((a + b2) + (c + d));
    }
}

// ---------------- fused kernel: prep (work-stealing) + gate + r13 main ----------------
__global__ __launch_bounds__(256, 3) void sake_fused(P p) {
    const int tid = threadIdx.x;

    __shared__ alignas(16) u16 s_A[256 * 72];       // prep scratch alias; spre/he; s_AT
    __shared__ alignas(16) u16 s_wsq[4 * 16 * 72];
    __shared__ alignas(16) u16 s_xs[256 * 4];
    __shared__ alignas(8)  u16 s_sa[256 * 4];
    __shared__ alignas(16) u16 s_att[4 * 272];
    __shared__ alignas(16) float s_rows[3 * 64];    // w1l | be1+lini | h_i
    __shared__ float s_cn[32];
    __shared__ float s_dv[4];
    __shared__ float s_scr[48];
    __shared__ float s_misc[8];
    __shared__ u32 s_flagv;
    __shared__ int s_ticket;

    const bool bf = block_flag(p.h, &s_flagv, tid);

    // ---- ticket: first NPREP blocks TO START do prep (deadlock-free by construction) ----
    if (tid == 0)
        s_ticket = (int)__hip_atomic_fetch_add(p.order, 1u, __ATOMIC_RELAXED, __HIP_MEMORY_SCOPE_AGENT);
    __syncthreads();
    const int tk = s_ticket;
    if (tk < NPREP) {
        prep_slice(tk, p, bf, tid, s_A);
        __syncthreads();
        if (tid == 0) {
            __threadfence();   // agent-scope release of prep writes
            __hip_atomic_fetch_add(p.done, 1u, __ATOMIC_RELEASE, __HIP_MEMORY_SCOPE_AGENT);
        }
    }
    // ---- gate ----
    if (tid == 0) {
        while (__hip_atomic_load(p.done, __ATOMIC_ACQUIRE, __HIP_MEMORY_SCOPE_AGENT) < NPREP)
            __builtin_amdgcn_s_sleep(2);
    }
    __syncthreads();

    // ================= main body (r13, verbatim) =================
    const int node = blockIdx.x;
    const int i = node & 255;
    const int b = node >> 8;
    const int j = tid;
    const int lane = tid & 63, wv = tid >> 6;
    const int l15 = lane & 15, l4 = lane >> 4;

    u16*   s_AT    = s_A;
    float* s_nin   = (float*)s_wsq;
    float* s_t1    = (float*)((char*)s_wsq + 1536);
    float* s_part  = (float*)((char*)s_wsq + 1792);
    float* s_combw = (float*)s_att;

    bf16x8 bw2[2][4];
    #pragma unroll
    for (int n = 0; n < 4; n++)
        #pragma unroll
        for (int ks = 0; ks < 2; ks++)
            bw2[ks][n] = *(const bf16x8*)(p.we2f + ((n * 2 + ks) * 64 + lane) * 8);
    float be2v[4];
    #pragma unroll
    for (int n = 0; n < 4; n++) be2v[n] = p.biasf[B_BE2 + 4 * l15 + n];

    // ---------- P0 ----------
    if (tid < 64) {
        s_rows[tid]       = p.biasf[B_W1L + tid];
        s_rows[64 + tid]  = p.biasf[B_BE1 + tid] + p.lini[node * 64 + tid];
        s_rows[128 + tid] = bf ? bfr(((const u16*)p.h)[node * 64 + tid])
                               : ((const float*)p.h)[node * 64 + tid];
    } else if (tid < 67) {
        s_misc[tid - 64] = p.xf[node * 3 + (tid - 64)];
    } else if (tid == 67) {
        s_misc[3] = p.vsc[node];
    } else if (tid < 72) {
        s_misc[4 + (tid - 68)] = p.biasf[B_GE + (tid - 68)];
    }
    __syncthreads();

    // ---------- P1 ----------
    float nrm;
    {
        float d0 = p.xf[(b * 256 + j) * 3 + 0] - s_misc[0];
        float d1 = p.xf[(b * 256 + j) * 3 + 1] - s_misc[1];
        float d2 = p.xf[(b * 256 + j) * 3 + 2] - s_misc[2];
        nrm = sqrtf(d0 * d0 + d1 * d1 + d2 * d2 + EPSc);
        float den = nrm + EPSc;
        float invd = frcp(den * den);
        uint2 xw;
        xw.x = cvtpk(d0 * invd, d1 * invd);
        xw.y = cvtpk(d2 * invd, nrm);
        *(uint2*)(&s_xs[j * 4]) = xw;

        const f32x4* lj = (const f32x4*)(p.linj + (b * 256 + j) * 64);
        const f32x4* rw = (const f32x4*)(s_rows);
        const f32x4* rb = (const f32x4*)(s_rows + 64);
        #pragma unroll
        for (int c = 0; c < 8; c++) {
            f32x4 a  = lj[2 * c],  bq = lj[2 * c + 1];
            f32x4 w0 = rw[2 * c],  w1 = rw[2 * c + 1];
            f32x4 b0 = rb[2 * c],  b1 = rb[2 * c + 1];
            float s[8];
            #pragma unroll
            for (int e = 0; e < 4; e++) s[e]     = silu(a[e]  + nrm * w0[e] + b0[e]);
            #pragma unroll
            for (int e = 0; e < 4; e++) s[4 + e] = silu(bq[e] + nrm * w1[e] + b1[e]);
            uint4 w;
            w.x = cvtpk(s[0], s[1]); w.y = cvtpk(s[2], s[3]);
            w.z = cvtpk(s[4], s[5]); w.w = cvtpk(s[6], s[7]);
            *(uint4*)(&s_A[j * 72 + c * 8]) = w;
        }
    }
    WAVE_FENCE();

    // ---------- GEMM1 ----------
    f32x4 acc[4][4] = {};
    #pragma unroll
    for (int mt = 0; mt < 4; mt++) {
        int row = (wv * 4 + mt) * 16 + l15;
        #pragma unroll
        for (int ks = 0; ks < 2; ks++) {
            bf16x8 a = *(const bf16x8*)(&s_A[row * 72 + ks * 32 + l4 * 8]);
            #pragma unroll
            for (int n = 0; n < 4; n++)
                acc[mt][n] = __builtin_amdgcn_mfma_f32_16x16x32_bf16(a, bw2[ks][n], acc[mt][n], 0, 0, 0);
        }
    }
    WAVE_FENCE();
    #pragma unroll
    for (int mt = 0; mt < 4; mt++)
        #pragma unroll
        for (int q = 0; q < 4; q++) {
            int row = (wv * 4 + mt) * 16 + l4 * 4 + q;
            uint2 pk;
            pk.x = cvtpk(silu(acc[mt][0][q] + be2v[0]), silu(acc[mt][1][q] + be2v[1]));
            pk.y = cvtpk(silu(acc[mt][2][q] + be2v[2]), silu(acc[mt][3][q] + be2v[3]));
            *(uint2*)(&s_A[row * 72 + 4 * l15]) = pk;
        }
    WAVE_FENCE();

    // ---------- S4 ----------
    {
        bf16x8 bw3[2][5], bw4[2][2];
        #pragma unroll
        for (int n = 0; n < 5; n++)
            #pragma unroll
            for (int ks = 0; ks < 2; ks++)
                bw3[ks][n] = *(const bf16x8*)(p.wc1f + ((n * 2 + ks) * 64 + lane) * 8);
        #pragma unroll
        for (int n = 0; n < 2; n++)
            #pragma unroll
            for (int ks = 0; ks < 2; ks++)
                bw4[ks][n] = *(const bf16x8*)(p.wc2f + ((n * 2 + ks) * 64 + lane) * 8);
        float bc1v[4], bc2v[2];
        #pragma unroll
        for (int n = 0; n < 4; n++) bc1v[n] = p.biasf[B_BC1 + 4 * l15 + n];
        #pragma unroll
        for (int n = 0; n < 2; n++) bc2v[n] = p.biasf[B_BC2 + n * 16 + l15];
        float bsv = p.biasf[B_BS + (l15 & 3)];

        u16* myws = s_wsq + wv * (16 * 72);
        float cmb[2][3] = {};
        #pragma unroll 1
        for (int mt = 0; mt < 4; mt++) {
            f32x4 c1x[5] = {};
            #pragma unroll
            for (int ks = 0; ks < 2; ks++) {
                bf16x8 a = *(const bf16x8*)(&s_A[((wv * 4 + mt) * 16 + l15) * 72 + ks * 32 + l4 * 8]);
                #pragma unroll
                for (int n = 0; n < 5; n++)
                    c1x[n] = __builtin_amdgcn_mfma_f32_16x16x32_bf16(a, bw3[ks][n], c1x[n], 0, 0, 0);
            }
            #pragma unroll
            for (int q = 0; q < 4; q++) {
                uint2 pk;
                pk.x = cvtpk(silu(c1x[0][q] + bc1v[0]), silu(c1x[1][q] + bc1v[1]));
                pk.y = cvtpk(silu(c1x[2][q] + bc1v[2]), silu(c1x[3][q] + bc1v[3]));
                *(uint2*)(&myws[(l4 * 4 + q) * 72 + 4 * l15]) = pk;
            }
            if (l15 < 4) {
                #pragma unroll
                for (int q = 0; q < 4; q++) {
                    int row = wv * 64 + mt * 16 + l4 * 4 + q;
                    float sub = (row == i) ? INFc : 0.f;
                    float lv = lrelu(c1x[4][q] + bsv) - sub;
                    s_sa[row * 4 + l15] = (u16)cvtpk(lv, lv);
                }
            }
            WAVE_FENCE();
            f32x4 co[2] = {};
            #pragma unroll
            for (int ks = 0; ks < 2; ks++) {
                bf16x8 a2 = *(const bf16x8*)(&myws[l15 * 72 + ks * 32 + l4 * 8]);
                #pragma unroll
                for (int n = 0; n < 2; n++)
                    co[n] = __builtin_amdgcn_mfma_f32_16x16x32_bf16(a2, bw4[ks][n], co[n], 0, 0, 0);
            }
            #pragma unroll
            for (int q = 0; q < 4; q++) {
                int r = wv * 64 + mt * 16 + l4 * 4 + q;
                uint2 xw = *(const uint2*)(&s_xs[r * 4]);
                float x0 = __uint_as_float(xw.x << 16);
                float x1 = __uint_as_float(xw.x & 0xffff0000u);
                float x2 = __uint_as_float(xw.y << 16);
                #pragma unroll
                for (int n = 0; n < 2; n++) {
                    float c = co[n][q] + bc2v[n];
                    cmb[n][0] += c * x0;
                    cmb[n][1] += c * x1;
                    cmb[n][2] += c * x2;
                }
            }
        }
        #pragma unroll
        for (int n = 0; n < 2; n++)
            #pragma unroll
            for (int k = 0; k < 3; k++) {
                float v = cmb[n][k];
                v += __shfl_xor(v, 16);
                v += __shfl_xor(v, 32);
                cmb[n][k] = v;
            }
        if (l4 == 0) {
            #pragma unroll
            for (int n = 0; n < 2; n++)
                #pragma unroll
                for (int k = 0; k < 3; k++)
                    s_combw[(wv * 32 + n * 16 + l15) * 3 + k] = cmb[n][k];
        }
    }
    __syncthreads();

    // ---------- S5 ----------
    uint4 her[8];
    #pragma unroll
    for (int c = 0; c < 8; c++) her[c] = *(const uint4*)(&s_A[j * 72 + c * 8]);
    float cnv = 0.f, dvv = 0.f;
    if (tid < 32) {
        float c0 = 0.f, c1 = 0.f, c2 = 0.f;
        #pragma unroll
        for (int w = 0; w < 4; w++) {
            c0 += s_combw[(w * 32 + tid) * 3 + 0];
            c1 += s_combw[(w * 32 + tid) * 3 + 1];
            c2 += s_combw[(w * 32 + tid) * 3 + 2];
        }
        cnv = c0 * c0 + c1 * c1 + c2 * c2;
    } else if (tid < 35) {
        int k = tid - 32;
        float a = 0.f;
        for (int w = 0; w < 4; w++)
            #pragma unroll 8
            for (int c = 0; c < 32; c++) a += s_combw[(w * 32 + c) * 3 + k];
        dvv = a * (1.0f / 8192.f);
    }
    __syncthreads();

    // ---------- S6 ----------
    #pragma unroll
    for (int c = 0; c < 8; c++) {
        u32 d[4] = { her[c].x, her[c].y, her[c].z, her[c].w };
        #pragma unroll
        for (int dw = 0; dw < 4; dw++) {
            int hh = c * 8 + dw * 2;
            s_AT[hh * 272 + j]       = (u16)(d[dw] & 0xffffu);
            s_AT[(hh + 1) * 272 + j] = (u16)(d[dw] >> 16);
        }
    }
    if (tid < 32) s_cn[tid] = cnv;
    else if (tid < 35) s_dv[tid - 32] = dvv;

    // ---------- P7 ----------
    {
        float pen = (j == i) ? INFc : 0.f;
        float elb = -(nrm + pen);
        float ge[4] = { s_misc[4], s_misc[5], s_misc[6], s_misc[7] };
        float sl[4];
        #pragma unroll
        for (int u = 0; u < 4; u++) sl[u] = bfr(s_sa[j * 4 + u]);

        float r4a[4] = { sl[0], sl[1], sl[2], sl[3] };
        blk_red<4>(r4a, true, s_scr, tid);

        float ae[4], as_[4];
        #pragma unroll
        for (int u = 0; u < 4; u++) ae[u] = __expf(ge[u] * elb);
        #pragma unroll
        for (int u = 0; u < 4; u++) as_[u] = __expf(sl[u] - r4a[u]);

        float r8[8] = { ae[0], ae[1], ae[2], ae[3], as_[0], as_[1], as_[2], as_[3] };
        blk_red<8>(r8, false, s_scr + 16, tid);

        float ep[4];
        #pragma unroll
        for (int u = 0; u < 4; u++)
            ep[u] = __expf(ae[u] * frcp(r8[u]) * as_[u] * frcp(r8[4 + u]));
        float r4b[4] = { ep[0], ep[1], ep[2], ep[3] };
        blk_red<4>(r4b, false, s_scr, tid);
        #pragma unroll
        for (int u = 0; u < 4; u++) {
            float av = ep[u] * frcp(r4b[u]);
            s_att[u * 272 + j] = (u16)cvtpk(av, av);
        }
    }
    __syncthreads();

    // ---------- P8 ----------
    {
        f32x4 hg = {};
        #pragma unroll
        for (int ks = 0; ks < 8; ks++) {
            bf16x8 af = *(const bf16x8*)(&s_AT[(wv * 16 + l15) * 272 + ks * 32 + l4 * 8]);
            bf16x8 bfv = *(const bf16x8*)(&s_att[(l15 & 3) * 272 + ks * 32 + l4 * 8]);
            hg = __builtin_amdgcn_mfma_f32_16x16x32_bf16(af, bfv, hg, 0, 0, 0);
        }
        if (l15 < 4) {
            #pragma unroll
            for (int q = 0; q < 4; q++)
                s_nin[64 + (wv * 16 + l4 * 4 + q) * 4 + l15] = hg[q];
        }
    }
    if (wv == 0) {
        float a[4] = {};
        #pragma unroll
        for (int e = 0; e < 8; e++) {
            int c = l4 * 8 + e;
            f32x4 w4 = *(const f32x4*)(p.wp1c + c * 64 + 4 * l15);
            float cv = s_cn[c];
            #pragma unroll
            for (int n = 0; n < 4; n++) a[n] += cv * w4[n];
        }
        #pragma unroll
        for (int n = 0; n < 4; n++) {
            a[n] += __shfl_xor(a[n], 16);
            a[n] += __shfl_xor(a[n], 32);
        }
        if (l4 == 0) {
            f32x4 tv;
            #pragma unroll
            for (int n = 0; n < 4; n++) tv[n] = silu(a[n] + p.biasf[B_BP1 + 4 * l15 + n]);
            *(f32x4*)(&s_t1[4 * l15]) = tv;
        }
    } else if (wv == 1) {
        s_nin[lane] = s_rows[128 + lane];
    }
    __syncthreads();

    // ---------- P9 ----------
    if (wv == 2) {
        float a[4] = {};
        #pragma unroll
        for (int it = 0; it < 16; it++) {
            int k = l4 * 16 + it;
            f32x4 w4 = *(const f32x4*)(p.wp2c + k * 64 + 4 * l15);
            float tk2 = s_t1[k];
            #pragma unroll
            for (int n = 0; n < 4; n++) a[n] += tk2 * w4[n];
        }
        #pragma unroll
        for (int n = 0; n < 4; n++) {
            a[n] += __shfl_xor(a[n], 16);
            a[n] += __shfl_xor(a[n], 32);
        }
        if (l4 == 0) {
            f32x4 hv;
            #pragma unroll
            for (int n = 0; n < 4; n++) hv[n] = a[n] + p.biasf[B_BP2 + 4 * l15 + n];
            *(f32x4*)(&s_nin[320 + 4 * l15]) = hv;
        }
        WAVE_FENCE();
    }
    {
        const int Q = (wv == 0) ? 0 : (wv == 1) ? 96 : (wv == 2) ? 288 : 192;
        int k0 = Q + l4 * 24;
        float a[4] = {};
        #pragma unroll
        for (int it = 0; it < 6; it++) {
            f32x4 inv = *(const f32x4*)(&s_nin[k0 + it * 4]);
            #pragma unroll
            for (int r = 0; r < 4; r++) {
                f32x4 w4 = *(const f32x4*)(p.wn1c + (k0 + it * 4 + r) * 64 + 4 * l15);
                #pragma unroll
                for (int n = 0; n < 4; n++) a[n] += inv[r] * w4[n];
            }
        }
        #pragma unroll
        for (int n = 0; n < 4; n++) {
            a[n] += __shfl_xor(a[n], 16);
            a[n] += __shfl_xor(a[n], 32);
        }
        if (l4 == 0) {
            f32x4 pv = { a[0], a[1], a[2], a[3] };
            *(f32x4*)(&s_part[wv * 64 + 4 * l15]) = pv;
        }
    }
    __syncthreads();

    // ---------- P10 ----------
    if (wv == 0) {
        float v2 = p.biasf[B_BN1 + lane] + (s_part[lane] + s_part[64 + lane])
                 + (s_part[128 + lane] + s_part[192 + lane]);
        s_t1[lane] = silu(v2);
        WAVE_FENCE();
        float a[4] = {};
        #pragma unroll
        for (int it = 0; it < 16; it++) {
            int k = l4 * 16 + it;
            f32x4 w4 = *(const f32x4*)(p.wn2c + k * 64 + 4 * l15);
            float tk2 = s_t1[k];
            #pragma unroll
            for (int n = 0; n < 4; n++) a[n] += tk2 * w4[n];
        }
        #pragma unroll
        for (int n = 0; n < 4; n++) {
            a[n] += __shfl_xor(a[n], 16);
            a[n] += __shfl_xor(a[n], 32);
        }
        if (l4 == 0) {
            float o[4];
            #pragma unroll
            for (int n = 0; n < 4; n++) {
                int oo = 4 * l15 + n;
                o[n] = s_rows[128 + oo] + p.biasf[B_BN2 + oo] + a[n];
            }
            if (bf) {
                uint2 w; w.x = cvtpk(o[0], o[1]); w.y = cvtpk(o[2], o[3]);
                *(uint2*)((u16*)p.out + node * 64 + 4 * l15) = w;
            } else {
                f32x4 w = { o[0], o[1], o[2], o[3] };
                *(f32x4*)((float*)p.out + node * 64 + 4 * l15) = w;
            }
        }
    } else if (wv == 1 && lane < 3) {
        int k = lane;
        float vn = s_dv[k] + s_misc[3] * p.vf[node * 3 + k];
        float xn = p.xf[node * 3 + k] + vn;
        STr(p.out, 65536 + node * 3 + k, xn, bf);
        STr(p.out, 68608 + node * 3 + k, vn, bf);
    }
}

extern "C" void kernel_launch(void* const* d_in, const int* in_sizes, int n_in,
                              void* d_out, int out_size, void* d_ws, size_t ws_size,
                              hipStream_t stream) {
    (void)in_sizes; (void)n_in; (void)out_size; (void)ws_size;
    char* ws = (char*)d_ws;

    P p;
    p.h   = d_in[0];  p.x   = d_in[1];  p.v   = d_in[2];
    p.We1 = d_in[3];  p.be1 = d_in[4];  p.We2 = d_in[5];  p.be2 = d_in[6];
    p.Wc1 = d_in[7];  p.bc1 = d_in[8];  p.Wc2 = d_in[9];  p.bc2 = d_in[10];
    p.Wp1 = d_in[11]; p.bp1 = d_in[12]; p.Wp2 = d_in[13]; p.bp2 = d_in[14];
    p.Ws_ = d_in[15]; p.bs_ = d_in[16];
    p.Wn1 = d_in[17]; p.bn1 = d_in[18]; p.Wn2 = d_in[19]; p.bn2 = d_in[20];
    p.Wv1 = d_in[21]; p.bv1 = d_in[22]; p.Wv2 = d_in[23]; p.lg  = d_in[24];
    p.linj  = (float*)(ws + O_LINJ);
    p.lini  = (float*)(ws + O_LINI);
    p.vsc   = (float*)(ws + O_VSC);
    p.wp1c  = (float*)(ws + O_WP1C);
    p.wp2c  = (float*)(ws + O_WP2C);
    p.wn1c  = (float*)(ws + O_WN1C);
    p.wn2c  = (float*)(ws + O_WN2C);
    p.xf    = (float*)(ws + O_XF);
    p.vf    = (float*)(ws + O_VF);
    p.biasf = (float*)(ws + O_BIAS);
    p.we2f  = (u16*)(ws + O_WE2F);
    p.wc1f  = (u16*)(ws + O_WC1F);
    p.wc2f  = (u16*)(ws + O_WC2F);
    p.order = (u32*)(ws + O_SYNC);
    p.done  = (u32*)(ws + O_SYNC + 4);
    p.out   = d_out;

    hipMemsetAsync(ws + O_SYNC, 0, 8, stream);   // zero order/done each launch (graph-safe)
    hipLaunchKernelGGL(sake_fused, dim3(1024), dim3(256), 0, stream, p);
}

// Round 15
// 50.776 us; speedup vs baseline: 5.3803x; 5.3803x over previous
//
#include <hip/hip_runtime.h>

typedef unsigned short u16;
typedef unsigned int   u32;
typedef __attribute__((ext_vector_type(8))) short bf16x8;
typedef __attribute__((ext_vector_type(4))) float f32x4;

#define EPSc 1e-5f
#define INFc 1e5f

// ---------------- ws byte offsets ----------------
#define O_LINJ  0         // f32[1024][64]
#define O_LINI  262144    // f32[1024][64]
#define O_VSC   524288    // f32[1024]
#define O_WE2F  528384    // u16[4*2*64*8]  (cols permuted: c = 4*l15+n)
#define O_WC1F  536576    // u16[5*2*64*8]  (n<4 permuted; tile4 = Ws|0)
#define O_WC2F  546816    // u16[2*2*64*8]  (natural)
#define O_WP1C  550912    // f32[32][64]
#define O_WP2C  559104    // f32[64][64]
#define O_WN2C  575488    // f32[64][64]
#define O_WN1C  591872    // f32[384][64]
#define O_XF    690176    // f32[1024*3]
#define O_VF    702464    // f32[1024*3]
#define O_BIAS  714752    // f32[552]
#define O_FLAG  741536    // u32

// biasf float indices
#define B_BE2 0
#define B_BC1 64
#define B_BC2 128
#define B_BS  160
#define B_GE  164
#define B_BP1 168
#define B_BP2 232
#define B_BN1 296
#define B_BN2 360
#define B_W1L 424
#define B_BE1 488

struct P {
    const void *h, *x, *v;
    const void *We1, *be1, *We2, *be2, *Wc1, *bc1, *Wc2, *bc2;
    const void *Wp1, *bp1, *Wp2, *bp2, *Ws_, *bs_;
    const void *Wn1, *bn1, *Wn2, *bn2, *Wv1, *bv1, *Wv2, *lg;
    float *linj, *lini, *vsc, *wp1c, *wp2c, *wn1c, *wn2c, *xf, *vf, *biasf;
    u16 *we2f, *wc1f, *wc2f;
    u32 *flagw;
    const u32 *flag;
    void *out;
};

__device__ __forceinline__ float bfr(u16 u) { return __uint_as_float(((u32)u) << 16); }
__device__ __forceinline__ u16 f2bf(float f) {
    u32 u = __float_as_uint(f);
    u = u + 0x7fffu + ((u >> 16) & 1u);
    return (u16)(u >> 16);
}
__device__ __forceinline__ u32 cvtpk(float lo, float hi) {
    u32 r;
    asm("v_cvt_pk_bf16_f32 %0, %1, %2" : "=v"(r) : "v"(lo), "v"(hi));
    return r;
}
__device__ __forceinline__ float frcp(float x) { return __builtin_amdgcn_rcpf(x); }
__device__ __forceinline__ float silu(float x) { return x * frcp(1.f + __expf(-x)); }
__device__ __forceinline__ float lrelu(float x) { return x > 0.f ? x : 0.2f * x; }

__device__ __forceinline__ float LDr(const void* p, int i, bool bf) {
    return bf ? bfr(((const u16*)p)[i]) : ((const float*)p)[i];
}
__device__ __forceinline__ u16 ENCr(const void* p, int i, bool bf) {
    return bf ? ((const u16*)p)[i] : f2bf(((const float*)p)[i]);
}
__device__ __forceinline__ void STr(void* p, int i, float v, bool bf) {
    if (bf) ((u16*)p)[i] = (u16)cvtpk(v, v);
    else    ((float*)p)[i] = v;
}
#define WAVE_FENCE() do { asm volatile("s_waitcnt lgkmcnt(0)" ::: "memory"); \
                          __builtin_amdgcn_sched_barrier(0); } while (0)

// per-block inline dtype detect (pure function of h)
__device__ __forceinline__ bool block_flag(const void* h, u32* s_flagv, int t) {
    if (t < 64) {
        const u16* ph = (const u16*)h;
        int cnt = 0;
        #pragma unroll
        for (int e = 0; e < 4; e++) {
            float v = bfr(ph[t * 4 + e]);
            float a = fabsf(v);
            if (v == 0.f || (a > 1e-6f && a < 1024.f)) cnt++;
        }
        #pragma unroll
        for (int o = 32; o; o >>= 1) cnt += __shfl_xor(cnt, o);
        if (t == 0) *s_flagv = (cnt >= 224) ? 1u : 0u;
    }
    __syncthreads();
    return *s_flagv != 0u;
}

// ---------------- merged prep: 22 blocks (r13, unchanged) ----------------
__global__ __launch_bounds__(256) void prep_all(P p) {
    __shared__ u32 s_flagv;
    const int t = threadIdx.x;
    const int blk = blockIdx.x;
    const bool bf = block_flag(p.h, &s_flagv, t);

    if (blk == 0) {
        if (t == 0) p.flagw[0] = bf ? 1u : 0u;
        for (int idx = t; idx < 4096; idx += 256) {
            int e = idx & 7, l = (idx >> 3) & 63, ks = (idx >> 9) & 1, nt = idx >> 10;
            int k = ks * 32 + (l >> 4) * 8 + e, c = (l & 15) * 4 + nt;
            p.we2f[idx] = ENCr(p.We2, k * 64 + c, bf);
        }
    } else if (blk == 1) {
        for (int idx = t; idx < 5120; idx += 256) {
            int e = idx & 7, l = (idx >> 3) & 63, ks = (idx >> 9) & 1, nt = idx >> 10;
            int k = ks * 32 + (l >> 4) * 8 + e;
            u16 v;
            if (nt < 4) v = ENCr(p.Wc1, k * 64 + (l & 15) * 4 + nt, bf);
            else { int cc = l & 15; v = (cc < 4) ? ENCr(p.Ws_, k * 4 + cc, bf) : (u16)0; }
            p.wc1f[idx] = v;
        }
    } else if (blk == 2) {
        for (int idx = t; idx < 2048; idx += 256) {
            int e = idx & 7, l = (idx >> 3) & 63, ks = (idx >> 9) & 1, nt = idx >> 10;
            int k = ks * 32 + (l >> 4) * 8 + e, c = nt * 16 + (l & 15);
            p.wc2f[idx] = ENCr(p.Wc2, k * 32 + c, bf);
        }
        if (t < 64) {
            p.biasf[B_BE2 + t] = LDr(p.be2, t, bf);
            p.biasf[B_BC1 + t] = LDr(p.bc1, t, bf);
            p.biasf[B_BP1 + t] = LDr(p.bp1, t, bf);
            p.biasf[B_BP2 + t] = LDr(p.bp2, t, bf);
            p.biasf[B_BN1 + t] = LDr(p.bn1, t, bf);
            p.biasf[B_BN2 + t] = LDr(p.bn2, t, bf);
            p.biasf[B_W1L + t] = LDr(p.We1, 128 * 64 + t, bf);
            p.biasf[B_BE1 + t] = LDr(p.be1, t, bf);
        } else if (t < 96) {
            p.biasf[B_BC2 + (t - 64)] = LDr(p.bc2, t - 64, bf);
        } else if (t < 100) {
            p.biasf[B_BS + (t - 96)] = LDr(p.bs_, t - 96, bf);
            p.biasf[B_GE + (t - 96)] = __expf(LDr(p.lg, t - 96, bf));
        }
        for (int i = t; i < 3072; i += 256) {
            p.xf[i] = LDr(p.x, i, bf);
            p.vf[i] = LDr(p.v, i, bf);
        }
    } else if (blk == 3) {
        for (int idx = t; idx < 2048; idx += 256) p.wp1c[idx] = LDr(p.Wp1, idx, bf);
        for (int idx = t; idx < 4096; idx += 256) p.wp2c[idx] = LDr(p.Wp2, idx, bf);
        for (int idx = t; idx < 4096; idx += 256) p.wn2c[idx] = LDr(p.Wn2, idx, bf);
    } else if (blk == 4) {
        for (int idx = t; idx < 12288; idx += 256) p.wn1c[idx] = LDr(p.Wn1, idx, bf);
    } else if (blk == 5) {
        for (int idx = t; idx < 12288; idx += 256) p.wn1c[12288 + idx] = LDr(p.Wn1, 12288 + idx, bf);
    } else {
        __shared__ alignas(16) u16 lds_wj[4096];
        __shared__ alignas(16) u16 lds_wi[4096];
        __shared__ alignas(16) u16 lds_wv[4096];
        __shared__ alignas(16) u16 shh[4][16 * 72];
        for (int idx = t; idx < 4096; idx += 256) {
            lds_wj[idx] = ENCr(p.We1, idx, bf);
            lds_wi[idx] = ENCr(p.We1, 4096 + idx, bf);
            lds_wv[idx] = ENCr(p.Wv1, idx, bf);
        }
        const int w = t >> 6, lane = t & 63;
        const int l15 = lane & 15, l4 = lane >> 4;
        const int n0 = (blk - 6) * 64 + w * 16;
        #pragma unroll
        for (int rr = 0; rr < 4; rr++) {
            int row = rr * 4 + l4;
            if (bf) {
                const u16* hb = (const u16*)p.h;
                *(uint2*)(&shh[w][row * 72 + l15 * 4]) =
                    *(const uint2*)(&hb[(n0 + row) * 64 + l15 * 4]);
            } else {
                const float* hf = (const float*)p.h;
                f32x4 hv = *(const f32x4*)(&hf[(n0 + row) * 64 + l15 * 4]);
                uint2 ww; ww.x = cvtpk(hv[0], hv[1]); ww.y = cvtpk(hv[2], hv[3]);
                *(uint2*)(&shh[w][row * 72 + l15 * 4]) = ww;
            }
        }
        __syncthreads();
        f32x4 dj[4] = {}, di[4] = {}, dv[4] = {};
        #pragma unroll
        for (int nt = 0; nt < 4; nt++) {
            #pragma unroll
            for (int ks = 0; ks < 2; ks++) {
                bf16x8 a = *(const bf16x8*)(&shh[w][l15 * 72 + ks * 32 + l4 * 8]);
                bf16x8 bj, bi2, bvv;
                #pragma unroll
                for (int e = 0; e < 8; e++) {
                    int off = (ks * 32 + l4 * 8 + e) * 64 + nt * 16 + l15;
                    bj[e]  = (short)lds_wj[off];
                    bi2[e] = (short)lds_wi[off];
                    bvv[e] = (short)lds_wv[off];
                }
                dj[nt] = __builtin_amdgcn_mfma_f32_16x16x32_bf16(a, bj,  dj[nt], 0, 0, 0);
                di[nt] = __builtin_amdgcn_mfma_f32_16x16x32_bf16(a, bi2, di[nt], 0, 0, 0);
                dv[nt] = __builtin_amdgcn_mfma_f32_16x16x32_bf16(a, bvv, dv[nt], 0, 0, 0);
            }
        }
        #pragma unroll
        for (int nt = 0; nt < 4; nt++)
            #pragma unroll
            for (int q = 0; q < 4; q++) {
                int n = n0 + l4 * 4 + q, c = nt * 16 + l15;
                p.linj[n * 64 + c] = dj[nt][q];
                p.lini[n * 64 + c] = di[nt][q];
            }
        float bv1v[4], wv2v[4];
        #pragma unroll
        for (int nt = 0; nt < 4; nt++) {
            bv1v[nt] = LDr(p.bv1, nt * 16 + l15, bf);
            wv2v[nt] = LDr(p.Wv2, nt * 16 + l15, bf);
        }
        #pragma unroll
        for (int q = 0; q < 4; q++) {
            float s = 0.f;
            #pragma unroll
            for (int nt = 0; nt < 4; nt++)
                s += silu(dv[nt][q] + bv1v[nt]) * wv2v[nt];
            s += __shfl_xor(s, 1);
            s += __shfl_xor(s, 2);
            s += __shfl_xor(s, 4);
            s += __shfl_xor(s, 8);
            if (l15 == 0) p.vsc[n0 + l4 * 4 + q] = s;
        }
    }
}

// N-channel block reduction, 256 threads
template<int N>
__device__ __forceinline__ void blk_red(float v[N], bool domax, float* scr, int tid) {
    #pragma unroll
    for (int s2 = 32; s2; s2 >>= 1)
        #pragma unroll
        for (int u = 0; u < N; u++) {
            float o = __shfl_xor(v[u], s2);
            v[u] = domax ? fmaxf(v[u], o) : (v[u] + o);
        }
    if ((tid & 63) == 0) {
        int w = tid >> 6;
        #pragma unroll
        for (int u = 0; u < N; u++) scr[w * N + u] = v[u];
    }
    __syncthreads();
    #pragma unroll
    for (int u = 0; u < N; u++) {
        float a = scr[0 * N + u], b2 = scr[1 * N + u], c = scr[2 * N + u], d = scr[3 * N + u];
        v[u] = domax ? fmaxf(fmaxf(a, b2), fmaxf(c, d)) : ((a + b2) + (c + d));
    }
}

// ---------------- main fused kernel (r13 + hoisted S4 loads + 2-reduce softmax) ----------------
__global__ __launch_bounds__(256, 3) void sake_all(P p) {
    const bool bf = (p.flag[0] != 0u);
    const int node = blockIdx.x;
    const int i = node & 255;
    const int b = node >> 8;
    const int tid = threadIdx.x;
    const int j = tid;
    const int lane = tid & 63, wv = tid >> 6;
    const int l15 = lane & 15, l4 = lane >> 4;

    __shared__ alignas(16) u16 s_A[256 * 72];
    __shared__ alignas(16) u16 s_wsq[4 * 16 * 72];
    __shared__ alignas(16) u16 s_xs[256 * 4];
    __shared__ alignas(8)  u16 s_sa[256 * 4];
    __shared__ alignas(16) u16 s_att[4 * 272];
    __shared__ alignas(16) float s_rows[3 * 64];   // w1l | be1+lini | h_i
    __shared__ float s_cn[32];
    __shared__ float s_dv[4];
    __shared__ float s_scr[48];
    __shared__ float s_misc[8];

    u16*   s_AT    = s_A;
    float* s_nin   = (float*)s_wsq;
    float* s_t1    = (float*)((char*)s_wsq + 1536);
    float* s_part  = (float*)((char*)s_wsq + 1792);
    float* s_combw = (float*)s_att;

    bf16x8 bw2[2][4];
    #pragma unroll
    for (int n = 0; n < 4; n++)
        #pragma unroll
        for (int ks = 0; ks < 2; ks++)
            bw2[ks][n] = *(const bf16x8*)(p.we2f + ((n * 2 + ks) * 64 + lane) * 8);
    float be2v[4];
    #pragma unroll
    for (int n = 0; n < 4; n++) be2v[n] = p.biasf[B_BE2 + 4 * l15 + n];

    // ---------- P0 ----------
    if (tid < 64) {
        s_rows[tid]       = p.biasf[B_W1L + tid];
        s_rows[64 + tid]  = p.biasf[B_BE1 + tid] + p.lini[node * 64 + tid];
        s_rows[128 + tid] = bf ? bfr(((const u16*)p.h)[node * 64 + tid])
                               : ((const float*)p.h)[node * 64 + tid];
    } else if (tid < 67) {
        s_misc[tid - 64] = p.xf[node * 3 + (tid - 64)];
    } else if (tid == 67) {
        s_misc[3] = p.vsc[node];
    } else if (tid < 72) {
        s_misc[4 + (tid - 68)] = p.biasf[B_GE + (tid - 68)];
    }
    __syncthreads();

    // ---------- P1 ----------
    float nrm;
    {
        float d0 = p.xf[(b * 256 + j) * 3 + 0] - s_misc[0];
        float d1 = p.xf[(b * 256 + j) * 3 + 1] - s_misc[1];
        float d2 = p.xf[(b * 256 + j) * 3 + 2] - s_misc[2];
        nrm = sqrtf(d0 * d0 + d1 * d1 + d2 * d2 + EPSc);
        float den = nrm + EPSc;
        float invd = frcp(den * den);
        uint2 xw;
        xw.x = cvtpk(d0 * invd, d1 * invd);
        xw.y = cvtpk(d2 * invd, nrm);
        *(uint2*)(&s_xs[j * 4]) = xw;

        const f32x4* lj = (const f32x4*)(p.linj + (b * 256 + j) * 64);
        const f32x4* rw = (const f32x4*)(s_rows);       // w1l
        const f32x4* rb = (const f32x4*)(s_rows + 64);  // be1 + lini
        #pragma unroll
        for (int c = 0; c < 8; c++) {
            f32x4 a  = lj[2 * c],  bq = lj[2 * c + 1];
            f32x4 w0 = rw[2 * c],  w1 = rw[2 * c + 1];
            f32x4 b0 = rb[2 * c],  b1 = rb[2 * c + 1];
            float s[8];
            #pragma unroll
            for (int e = 0; e < 4; e++) s[e]     = silu(a[e]  + nrm * w0[e] + b0[e]);
            #pragma unroll
            for (int e = 0; e < 4; e++) s[4 + e] = silu(bq[e] + nrm * w1[e] + b1[e]);
            uint4 w;
            w.x = cvtpk(s[0], s[1]); w.y = cvtpk(s[2], s[3]);
            w.z = cvtpk(s[4], s[5]); w.w = cvtpk(s[6], s[7]);
            *(uint4*)(&s_A[j * 72 + c * 8]) = w;
        }
    }
    WAVE_FENCE();

    // ---------- GEMM1 MFMAs ----------
    f32x4 acc[4][4] = {};
    #pragma unroll
    for (int mt = 0; mt < 4; mt++) {
        int row = (wv * 4 + mt) * 16 + l15;
        #pragma unroll
        for (int ks = 0; ks < 2; ks++) {
            bf16x8 a = *(const bf16x8*)(&s_A[row * 72 + ks * 32 + l4 * 8]);
            #pragma unroll
            for (int n = 0; n < 4; n++)
                acc[mt][n] = __builtin_amdgcn_mfma_f32_16x16x32_bf16(a, bw2[ks][n], acc[mt][n], 0, 0, 0);
        }
    }
    // ---- issue S4 weight loads NOW (vmcnt-tracked; unaffected by lgkmcnt fences;
    //      latency hidden under GEMM1 writeback instead of exposed at S4 entry) ----
    bf16x8 bw3[2][5], bw4[2][2];
    #pragma unroll
    for (int n = 0; n < 5; n++)
        #pragma unroll
        for (int ks = 0; ks < 2; ks++)
            bw3[ks][n] = *(const bf16x8*)(p.wc1f + ((n * 2 + ks) * 64 + lane) * 8);
    #pragma unroll
    for (int n = 0; n < 2; n++)
        #pragma unroll
        for (int ks = 0; ks < 2; ks++)
            bw4[ks][n] = *(const bf16x8*)(p.wc2f + ((n * 2 + ks) * 64 + lane) * 8);
    float bc1v[4], bc2v[2];
    #pragma unroll
    for (int n = 0; n < 4; n++) bc1v[n] = p.biasf[B_BC1 + 4 * l15 + n];
    #pragma unroll
    for (int n = 0; n < 2; n++) bc2v[n] = p.biasf[B_BC2 + n * 16 + l15];
    float bsv = p.biasf[B_BS + (l15 & 3)];

    WAVE_FENCE();
    // ---------- GEMM1 writeback ----------
    #pragma unroll
    for (int mt = 0; mt < 4; mt++)
        #pragma unroll
        for (int q = 0; q < 4; q++) {
            int row = (wv * 4 + mt) * 16 + l4 * 4 + q;
            uint2 pk;
            pk.x = cvtpk(silu(acc[mt][0][q] + be2v[0]), silu(acc[mt][1][q] + be2v[1]));
            pk.y = cvtpk(silu(acc[mt][2][q] + be2v[2]), silu(acc[mt][3][q] + be2v[3]));
            *(uint2*)(&s_A[row * 72 + 4 * l15]) = pk;
        }
    WAVE_FENCE();

    // ---------- S4 ----------
    {
        u16* myws = s_wsq + wv * (16 * 72);
        float cmb[2][3] = {};
        #pragma unroll 1
        for (int mt = 0; mt < 4; mt++) {
            f32x4 c1x[5] = {};
            #pragma unroll
            for (int ks = 0; ks < 2; ks++) {
                bf16x8 a = *(const bf16x8*)(&s_A[((wv * 4 + mt) * 16 + l15) * 72 + ks * 32 + l4 * 8]);
                #pragma unroll
                for (int n = 0; n < 5; n++)
                    c1x[n] = __builtin_amdgcn_mfma_f32_16x16x32_bf16(a, bw3[ks][n], c1x[n], 0, 0, 0);
            }
            #pragma unroll
            for (int q = 0; q < 4; q++) {
                uint2 pk;
                pk.x = cvtpk(silu(c1x[0][q] + bc1v[0]), silu(c1x[1][q] + bc1v[1]));
                pk.y = cvtpk(silu(c1x[2][q] + bc1v[2]), silu(c1x[3][q] + bc1v[3]));
                *(uint2*)(&myws[(l4 * 4 + q) * 72 + 4 * l15]) = pk;
            }
            if (l15 < 4) {
                #pragma unroll
                for (int q = 0; q < 4; q++) {
                    int row = wv * 64 + mt * 16 + l4 * 4 + q;
                    float sub = (row == i) ? INFc : 0.f;
                    float lv = lrelu(c1x[4][q] + bsv) - sub;
                    s_sa[row * 4 + l15] = (u16)cvtpk(lv, lv);
                }
            }
            WAVE_FENCE();
            f32x4 co[2] = {};
            #pragma unroll
            for (int ks = 0; ks < 2; ks++) {
                bf16x8 a2 = *(const bf16x8*)(&myws[l15 * 72 + ks * 32 + l4 * 8]);
                #pragma unroll
                for (int n = 0; n < 2; n++)
                    co[n] = __builtin_amdgcn_mfma_f32_16x16x32_bf16(a2, bw4[ks][n], co[n], 0, 0, 0);
            }
            #pragma unroll
            for (int q = 0; q < 4; q++) {
                int r = wv * 64 + mt * 16 + l4 * 4 + q;
                uint2 xw = *(const uint2*)(&s_xs[r * 4]);
                float x0 = __uint_as_float(xw.x << 16);
                float x1 = __uint_as_float(xw.x & 0xffff0000u);
                float x2 = __uint_as_float(xw.y << 16);
                #pragma unroll
                for (int n = 0; n < 2; n++) {
                    float c = co[n][q] + bc2v[n];
                    cmb[n][0] += c * x0;
                    cmb[n][1] += c * x1;
                    cmb[n][2] += c * x2;
                }
            }
        }
        #pragma unroll
        for (int n = 0; n < 2; n++)
            #pragma unroll
            for (int k = 0; k < 3; k++) {
                float v = cmb[n][k];
                v += __shfl_xor(v, 16);
                v += __shfl_xor(v, 32);
                cmb[n][k] = v;
            }
        if (l4 == 0) {
            #pragma unroll
            for (int n = 0; n < 2; n++)
                #pragma unroll
                for (int k = 0; k < 3; k++)
                    s_combw[(wv * 32 + n * 16 + l15) * 3 + k] = cmb[n][k];
        }
    }
    __syncthreads();

    // ---------- S5 ----------
    uint4 her[8];
    #pragma unroll
    for (int c = 0; c < 8; c++) her[c] = *(const uint4*)(&s_A[j * 72 + c * 8]);
    float cnv = 0.f, dvv = 0.f;
    if (tid < 32) {
        float c0 = 0.f, c1 = 0.f, c2 = 0.f;
        #pragma unroll
        for (int w = 0; w < 4; w++) {
            c0 += s_combw[(w * 32 + tid) * 3 + 0];
            c1 += s_combw[(w * 32 + tid) * 3 + 1];
            c2 += s_combw[(w * 32 + tid) * 3 + 2];
        }
        cnv = c0 * c0 + c1 * c1 + c2 * c2;
    } else if (tid < 35) {
        int k = tid - 32;
        float a = 0.f;
        for (int w = 0; w < 4; w++)
            #pragma unroll 8
            for (int c = 0; c < 32; c++) a += s_combw[(w * 32 + c) * 3 + k];
        dvv = a * (1.0f / 8192.f);
    }
    __syncthreads();

    // ---------- S6 ----------
    #pragma unroll
    for (int c = 0; c < 8; c++) {
        u32 d[4] = { her[c].x, her[c].y, her[c].z, her[c].w };
        #pragma unroll
        for (int dw = 0; dw < 4; dw++) {
            int hh = c * 8 + dw * 2;
            s_AT[hh * 272 + j]       = (u16)(d[dw] & 0xffffu);
            s_AT[(hh + 1) * 272 + j] = (u16)(d[dw] >> 16);
        }
    }
    if (tid < 32) s_cn[tid] = cnv;
    else if (tid < 35) s_dv[tid - 32] = dvv;

    // ---------- P7: softmaxes (2 reductions; sl bounded so no max pass needed) ----------
    {
        float pen = (j == i) ? INFc : 0.f;
        float elb = -(nrm + pen);
        float ge[4] = { s_misc[4], s_misc[5], s_misc[6], s_misc[7] };
        float sl[4];
        #pragma unroll
        for (int u = 0; u < 4; u++) sl[u] = bfr(s_sa[j * 4 + u]);

        float ae[4], as_[4];
        #pragma unroll
        for (int u = 0; u < 4; u++) ae[u] = __expf(ge[u] * elb);
        #pragma unroll
        for (int u = 0; u < 4; u++) as_[u] = __expf(sl[u]);   // |sl| <~ 2; diag -1e5 -> 0

        float r8[8] = { ae[0], ae[1], ae[2], ae[3], as_[0], as_[1], as_[2], as_[3] };
        blk_red<8>(r8, false, s_scr, tid);

        float ep[4];
        #pragma unroll
        for (int u = 0; u < 4; u++)
            ep[u] = __expf(ae[u] * frcp(r8[u]) * as_[u] * frcp(r8[4 + u]));
        float r4b[4] = { ep[0], ep[1], ep[2], ep[3] };
        blk_red<4>(r4b, false, s_scr + 32, tid);
        #pragma unroll
        for (int u = 0; u < 4; u++) {
            float av = ep[u] * frcp(r4b[u]);
            s_att[u * 272 + j] = (u16)cvtpk(av, av);
        }
    }
    __syncthreads();

    // ---------- P8 ----------
    {
        f32x4 hg = {};
        #pragma unroll
        for (int ks = 0; ks < 8; ks++) {
            bf16x8 af = *(const bf16x8*)(&s_AT[(wv * 16 + l15) * 272 + ks * 32 + l4 * 8]);
            bf16x8 bfv = *(const bf16x8*)(&s_att[(l15 & 3) * 272 + ks * 32 + l4 * 8]);
            hg = __builtin_amdgcn_mfma_f32_16x16x32_bf16(af, bfv, hg, 0, 0, 0);
        }
        if (l15 < 4) {
            #pragma unroll
            for (int q = 0; q < 4; q++)
                s_nin[64 + (wv * 16 + l4 * 4 + q) * 4 + l15] = hg[q];
        }
    }
    if (wv == 0) {
        float a[4] = {};
        #pragma unroll
        for (int e = 0; e < 8; e++) {
            int c = l4 * 8 + e;
            f32x4 w4 = *(const f32x4*)(p.wp1c + c * 64 + 4 * l15);
            float cv = s_cn[c];
            #pragma unroll
            for (int n = 0; n < 4; n++) a[n] += cv * w4[n];
        }
        #pragma unroll
        for (int n = 0; n < 4; n++) {
            a[n] += __shfl_xor(a[n], 16);
            a[n] += __shfl_xor(a[n], 32);
        }
        if (l4 == 0) {
            f32x4 tv;
            #pragma unroll
            for (int n = 0; n < 4; n++) tv[n] = silu(a[n] + p.biasf[B_BP1 + 4 * l15 + n]);
            *(f32x4*)(&s_t1[4 * l15]) = tv;
        }
    } else if (wv == 1) {
        s_nin[lane] = s_rows[128 + lane];
    }
    __syncthreads();

    // ---------- P9 ----------
    if (wv == 2) {
        float a[4] = {};
        #pragma unroll
        for (int it = 0; it < 16; it++) {
            int k = l4 * 16 + it;
            f32x4 w4 = *(const f32x4*)(p.wp2c + k * 64 + 4 * l15);
            float tk = s_t1[k];
            #pragma unroll
            for (int n = 0; n < 4; n++) a[n] += tk * w4[n];
        }
        #pragma unroll
        for (int n = 0; n < 4; n++) {
            a[n] += __shfl_xor(a[n], 16);
            a[n] += __shfl_xor(a[n], 32);
        }
        if (l4 == 0) {
            f32x4 hv;
            #pragma unroll
            for (int n = 0; n < 4; n++) hv[n] = a[n] + p.biasf[B_BP2 + 4 * l15 + n];
            *(f32x4*)(&s_nin[320 + 4 * l15]) = hv;
        }
        WAVE_FENCE();
    }
    {
        const int Q = (wv == 0) ? 0 : (wv == 1) ? 96 : (wv == 2) ? 288 : 192;
        int k0 = Q + l4 * 24;
        float a[4] = {};
        #pragma unroll
        for (int it = 0; it < 6; it++) {
            f32x4 inv = *(const f32x4*)(&s_nin[k0 + it * 4]);
            #pragma unroll
            for (int r = 0; r < 4; r++) {
                f32x4 w4 = *(const f32x4*)(p.wn1c + (k0 + it * 4 + r) * 64 + 4 * l15);
                #pragma unroll
                for (int n = 0; n < 4; n++) a[n] += inv[r] * w4[n];
            }
        }
        #pragma unroll
        for (int n = 0; n < 4; n++) {
            a[n] += __shfl_xor(a[n], 16);
            a[n] += __shfl_xor(a[n], 32);
        }
        if (l4 == 0) {
            f32x4 pv = { a[0], a[1], a[2], a[3] };
            *(f32x4*)(&s_part[wv * 64 + 4 * l15]) = pv;
        }
    }
    __syncthreads();

    // ---------- P10 ----------
    if (wv == 0) {
        float v2 = p.biasf[B_BN1 + lane] + (s_part[lane] + s_part[64 + lane])
                 + (s_part[128 + lane] + s_part[192 + lane]);
        s_t1[lane] = silu(v2);
        WAVE_FENCE();
        float a[4] = {};
        #pragma unroll
        for (int it = 0; it < 16; it++) {
            int k = l4 * 16 + it;
            f32x4 w4 = *(const f32x4*)(p.wn2c + k * 64 + 4 * l15);
            float tk = s_t1[k];
            #pragma unroll
            for (int n = 0; n < 4; n++) a[n] += tk * w4[n];
        }
        #pragma unroll
        for (int n = 0; n < 4; n++) {
            a[n] += __shfl_xor(a[n], 16);
            a[n] += __shfl_xor(a[n], 32);
        }
        if (l4 == 0) {
            float o[4];
            #pragma unroll
            for (int n = 0; n < 4; n++) {
                int oo = 4 * l15 + n;
                o[n] = s_rows[128 + oo] + p.biasf[B_BN2 + oo] + a[n];
            }
            if (bf) {
                uint2 w; w.x = cvtpk(o[0], o[1]); w.y = cvtpk(o[2], o[3]);
                *(uint2*)((u16*)p.out + node * 64 + 4 * l15) = w;
            } else {
                f32x4 w = { o[0], o[1], o[2], o[3] };
                *(f32x4*)((float*)p.out + node * 64 + 4 * l15) = w;
            }
        }
    } else if (wv == 1 && lane < 3) {
        int k = lane;
        float vn = s_dv[k] + s_misc[3] * p.vf[node * 3 + k];
        float xn = p.xf[node * 3 + k] + vn;
        STr(p.out, 65536 + node * 3 + k, xn, bf);
        STr(p.out, 68608 + node * 3 + k, vn, bf);
    }
}

extern "C" void kernel_launch(void* const* d_in, const int* in_sizes, int n_in,
                              void* d_out, int out_size, void* d_ws, size_t ws_size,
                              hipStream_t stream) {
    (void)in_sizes; (void)n_in; (void)out_size; (void)ws_size;
    char* ws = (char*)d_ws;

    P p;
    p.h   = d_in[0];  p.x   = d_in[1];  p.v   = d_in[2];
    p.We1 = d_in[3];  p.be1 = d_in[4];  p.We2 = d_in[5];  p.be2 = d_in[6];
    p.Wc1 = d_in[7];  p.bc1 = d_in[8];  p.Wc2 = d_in[9];  p.bc2 = d_in[10];
    p.Wp1 = d_in[11]; p.bp1 = d_in[12]; p.Wp2 = d_in[13]; p.bp2 = d_in[14];
    p.Ws_ = d_in[15]; p.bs_ = d_in[16];
    p.Wn1 = d_in[17]; p.bn1 = d_in[18]; p.Wn2 = d_in[19]; p.bn2 = d_in[20];
    p.Wv1 = d_in[21]; p.bv1 = d_in[22]; p.Wv2 = d_in[23]; p.lg  = d_in[24];
    p.linj  = (float*)(ws + O_LINJ);
    p.lini  = (float*)(ws + O_LINI);
    p.vsc   = (float*)(ws + O_VSC);
    p.wp1c  = (float*)(ws + O_WP1C);
    p.wp2c  = (float*)(ws + O_WP2C);
    p.wn1c  = (float*)(ws + O_WN1C);
    p.wn2c  = (float*)(ws + O_WN2C);
    p.xf    = (float*)(ws + O_XF);
    p.vf    = (float*)(ws + O_VF);
    p.biasf = (float*)(ws + O_BIAS);
    p.we2f  = (u16*)(ws + O_WE2F);
    p.wc1f  = (u16*)(ws + O_WC1F);
    p.wc2f  = (u16*)(ws + O_WC2F);
    p.flagw = (u32*)(ws + O_FLAG);
    p.flag  = (const u32*)(ws + O_FLAG);
    p.out   = d_out;

    hipLaunchKernelGGL(prep_all, dim3(22), dim3(256), 0, stream, p);
    hipLaunchKernelGGL(sake_all, dim3(1024), dim3(256), 0, stream, p);
}

// Round 16
// 48.964 us; speedup vs baseline: 5.5793x; 1.0370x over previous
//
#include <hip/hip_runtime.h>

typedef unsigned short u16;
typedef unsigned int   u32;
typedef __attribute__((ext_vector_type(8))) short bf16x8;
typedef __attribute__((ext_vector_type(4))) float f32x4;

#define EPSc 1e-5f
#define INFc 1e5f

// ---------------- ws byte offsets ----------------
#define O_LINJ  0         // f32[1024][64]
#define O_LINI  262144    // f32[1024][64]
#define O_VSC   524288    // f32[1024]
#define O_WE2F  528384    // u16[4*2*64*8]  (cols permuted: c = 4*l15+n)
#define O_WC1F  536576    // u16[5*2*64*8]  (n<4 permuted; tile4 = Ws|0)
#define O_WC2F  546816    // u16[2*2*64*8]  (natural)
#define O_WP1C  550912    // f32[32][64]
#define O_WP2C  559104    // f32[64][64]
#define O_WN2C  575488    // f32[64][64]
#define O_WN1C  591872    // f32[384][64]
#define O_XF    690176    // f32[1024*3]
#define O_VF    702464    // f32[1024*3]
#define O_BIAS  714752    // f32[552]
#define O_FLAG  741536    // u32

// biasf float indices
#define B_BE2 0
#define B_BC1 64
#define B_BC2 128
#define B_BS  160
#define B_GE  164
#define B_BP1 168
#define B_BP2 232
#define B_BN1 296
#define B_BN2 360
#define B_W1L 424
#define B_BE1 488

struct P {
    const void *h, *x, *v;
    const void *We1, *be1, *We2, *be2, *Wc1, *bc1, *Wc2, *bc2;
    const void *Wp1, *bp1, *Wp2, *bp2, *Ws_, *bs_;
    const void *Wn1, *bn1, *Wn2, *bn2, *Wv1, *bv1, *Wv2, *lg;
    float *linj, *lini, *vsc, *wp1c, *wp2c, *wn1c, *wn2c, *xf, *vf, *biasf;
    u16 *we2f, *wc1f, *wc2f;
    u32 *flagw;
    const u32 *flag;
    void *out;
};

__device__ __forceinline__ float bfr(u16 u) { return __uint_as_float(((u32)u) << 16); }
__device__ __forceinline__ u16 f2bf(float f) {
    u32 u = __float_as_uint(f);
    u = u + 0x7fffu + ((u >> 16) & 1u);
    return (u16)(u >> 16);
}
__device__ __forceinline__ u32 cvtpk(float lo, float hi) {
    u32 r;
    asm("v_cvt_pk_bf16_f32 %0, %1, %2" : "=v"(r) : "v"(lo), "v"(hi));
    return r;
}
__device__ __forceinline__ float frcp(float x) { return __builtin_amdgcn_rcpf(x); }
__device__ __forceinline__ float silu(float x) { return x * frcp(1.f + __expf(-x)); }
__device__ __forceinline__ float lrelu(float x) { return x > 0.f ? x : 0.2f * x; }

__device__ __forceinline__ float LDr(const void* p, int i, bool bf) {
    return bf ? bfr(((const u16*)p)[i]) : ((const float*)p)[i];
}
__device__ __forceinline__ u16 ENCr(const void* p, int i, bool bf) {
    return bf ? ((const u16*)p)[i] : f2bf(((const float*)p)[i]);
}
__device__ __forceinline__ void STr(void* p, int i, float v, bool bf) {
    if (bf) ((u16*)p)[i] = (u16)cvtpk(v, v);
    else    ((float*)p)[i] = v;
}
#define WAVE_FENCE() do { asm volatile("s_waitcnt lgkmcnt(0)" ::: "memory"); \
                          __builtin_amdgcn_sched_barrier(0); } while (0)

// per-block inline dtype detect (pure function of h)
__device__ __forceinline__ bool block_flag(const void* h, u32* s_flagv, int t) {
    if (t < 64) {
        const u16* ph = (const u16*)h;
        int cnt = 0;
        #pragma unroll
        for (int e = 0; e < 4; e++) {
            float v = bfr(ph[t * 4 + e]);
            float a = fabsf(v);
            if (v == 0.f || (a > 1e-6f && a < 1024.f)) cnt++;
        }
        #pragma unroll
        for (int o = 32; o; o >>= 1) cnt += __shfl_xor(cnt, o);
        if (t == 0) *s_flagv = (cnt >= 224) ? 1u : 0u;
    }
    __syncthreads();
    return *s_flagv != 0u;
}

// ---------------- merged prep: 26 blocks (finer split than r13) ----------------
__global__ __launch_bounds__(256) void prep_all(P p) {
    __shared__ u32 s_flagv;
    const int t = threadIdx.x;
    const int blk = blockIdx.x;
    const bool bf = block_flag(p.h, &s_flagv, t);

    if (blk == 0) {
        if (t == 0) p.flagw[0] = bf ? 1u : 0u;
        for (int idx = t; idx < 4096; idx += 256) {
            int e = idx & 7, l = (idx >> 3) & 63, ks = (idx >> 9) & 1, nt = idx >> 10;
            int k = ks * 32 + (l >> 4) * 8 + e, c = (l & 15) * 4 + nt;
            p.we2f[idx] = ENCr(p.We2, k * 64 + c, bf);
        }
    } else if (blk == 1) {
        for (int idx = t; idx < 5120; idx += 256) {
            int e = idx & 7, l = (idx >> 3) & 63, ks = (idx >> 9) & 1, nt = idx >> 10;
            int k = ks * 32 + (l >> 4) * 8 + e;
            u16 v;
            if (nt < 4) v = ENCr(p.Wc1, k * 64 + (l & 15) * 4 + nt, bf);
            else { int cc = l & 15; v = (cc < 4) ? ENCr(p.Ws_, k * 4 + cc, bf) : (u16)0; }
            p.wc1f[idx] = v;
        }
    } else if (blk == 2) {
        for (int idx = t; idx < 2048; idx += 256) {
            int e = idx & 7, l = (idx >> 3) & 63, ks = (idx >> 9) & 1, nt = idx >> 10;
            int k = ks * 32 + (l >> 4) * 8 + e, c = nt * 16 + (l & 15);
            p.wc2f[idx] = ENCr(p.Wc2, k * 32 + c, bf);
        }
        if (t < 64) {
            p.biasf[B_BE2 + t] = LDr(p.be2, t, bf);
            p.biasf[B_BC1 + t] = LDr(p.bc1, t, bf);
            p.biasf[B_BP1 + t] = LDr(p.bp1, t, bf);
            p.biasf[B_BP2 + t] = LDr(p.bp2, t, bf);
            p.biasf[B_BN1 + t] = LDr(p.bn1, t, bf);
            p.biasf[B_BN2 + t] = LDr(p.bn2, t, bf);
            p.biasf[B_W1L + t] = LDr(p.We1, 128 * 64 + t, bf);
            p.biasf[B_BE1 + t] = LDr(p.be1, t, bf);
        } else if (t < 96) {
            p.biasf[B_BC2 + (t - 64)] = LDr(p.bc2, t - 64, bf);
        } else if (t < 100) {
            p.biasf[B_BS + (t - 96)] = LDr(p.bs_, t - 96, bf);
            p.biasf[B_GE + (t - 96)] = __expf(LDr(p.lg, t - 96, bf));
        }
    } else if (blk == 3) {
        for (int i = t; i < 3072; i += 256) {
            p.xf[i] = LDr(p.x, i, bf);
            p.vf[i] = LDr(p.v, i, bf);
        }
    } else if (blk == 4) {
        for (int idx = t; idx < 2048; idx += 256) p.wp1c[idx] = LDr(p.Wp1, idx, bf);
        for (int idx = t; idx < 4096; idx += 256) p.wp2c[idx] = LDr(p.Wp2, idx, bf);
    } else if (blk == 5) {
        for (int idx = t; idx < 4096; idx += 256) p.wn2c[idx] = LDr(p.Wn2, idx, bf);
    } else if (blk < 10) {
        int base = (blk - 6) * 6144;
        for (int idx = t; idx < 6144; idx += 256) p.wn1c[base + idx] = LDr(p.Wn1, base + idx, bf);
    } else {
        // node blocks (16): 4 waves x 16 nodes; raw weights staged in LDS
        __shared__ alignas(16) u16 lds_wj[4096];
        __shared__ alignas(16) u16 lds_wi[4096];
        __shared__ alignas(16) u16 lds_wv[4096];
        __shared__ alignas(16) u16 shh[4][16 * 72];
        for (int idx = t; idx < 4096; idx += 256) {
            lds_wj[idx] = ENCr(p.We1, idx, bf);
            lds_wi[idx] = ENCr(p.We1, 4096 + idx, bf);
            lds_wv[idx] = ENCr(p.Wv1, idx, bf);
        }
        const int w = t >> 6, lane = t & 63;
        const int l15 = lane & 15, l4 = lane >> 4;
        const int n0 = (blk - 10) * 64 + w * 16;
        #pragma unroll
        for (int rr = 0; rr < 4; rr++) {
            int row = rr * 4 + l4;
            if (bf) {
                const u16* hb = (const u16*)p.h;
                *(uint2*)(&shh[w][row * 72 + l15 * 4]) =
                    *(const uint2*)(&hb[(n0 + row) * 64 + l15 * 4]);
            } else {
                const float* hf = (const float*)p.h;
                f32x4 hv = *(const f32x4*)(&hf[(n0 + row) * 64 + l15 * 4]);
                uint2 ww; ww.x = cvtpk(hv[0], hv[1]); ww.y = cvtpk(hv[2], hv[3]);
                *(uint2*)(&shh[w][row * 72 + l15 * 4]) = ww;
            }
        }
        __syncthreads();
        f32x4 dj[4] = {}, di[4] = {}, dv[4] = {};
        #pragma unroll
        for (int nt = 0; nt < 4; nt++) {
            #pragma unroll
            for (int ks = 0; ks < 2; ks++) {
                bf16x8 a = *(const bf16x8*)(&shh[w][l15 * 72 + ks * 32 + l4 * 8]);
                bf16x8 bj, bi2, bvv;
                #pragma unroll
                for (int e = 0; e < 8; e++) {
                    int off = (ks * 32 + l4 * 8 + e) * 64 + nt * 16 + l15;
                    bj[e]  = (short)lds_wj[off];
                    bi2[e] = (short)lds_wi[off];
                    bvv[e] = (short)lds_wv[off];
                }
                dj[nt] = __builtin_amdgcn_mfma_f32_16x16x32_bf16(a, bj,  dj[nt], 0, 0, 0);
                di[nt] = __builtin_amdgcn_mfma_f32_16x16x32_bf16(a, bi2, di[nt], 0, 0, 0);
                dv[nt] = __builtin_amdgcn_mfma_f32_16x16x32_bf16(a, bvv, dv[nt], 0, 0, 0);
            }
        }
        #pragma unroll
        for (int nt = 0; nt < 4; nt++)
            #pragma unroll
            for (int q = 0; q < 4; q++) {
                int n = n0 + l4 * 4 + q, c = nt * 16 + l15;
                p.linj[n * 64 + c] = dj[nt][q];
                p.lini[n * 64 + c] = di[nt][q];
            }
        float bv1v[4], wv2v[4];
        #pragma unroll
        for (int nt = 0; nt < 4; nt++) {
            bv1v[nt] = LDr(p.bv1, nt * 16 + l15, bf);
            wv2v[nt] = LDr(p.Wv2, nt * 16 + l15, bf);
        }
        #pragma unroll
        for (int q = 0; q < 4; q++) {
            float s = 0.f;
            #pragma unroll
            for (int nt = 0; nt < 4; nt++)
                s += silu(dv[nt][q] + bv1v[nt]) * wv2v[nt];
            s += __shfl_xor(s, 1);
            s += __shfl_xor(s, 2);
            s += __shfl_xor(s, 4);
            s += __shfl_xor(s, 8);
            if (l15 == 0) p.vsc[n0 + l4 * 4 + q] = s;
        }
    }
}

// N-channel block reduction, 256 threads
template<int N>
__device__ __forceinline__ void blk_red(float v[N], bool domax, float* scr, int tid) {
    #pragma unroll
    for (int s2 = 32; s2; s2 >>= 1)
        #pragma unroll
        for (int u = 0; u < N; u++) {
            float o = __shfl_xor(v[u], s2);
            v[u] = domax ? fmaxf(v[u], o) : (v[u] + o);
        }
    if ((tid & 63) == 0) {
        int w = tid >> 6;
        #pragma unroll
        for (int u = 0; u < N; u++) scr[w * N + u] = v[u];
    }
    __syncthreads();
    #pragma unroll
    for (int u = 0; u < N; u++) {
        float a = scr[0 * N + u], b2 = scr[1 * N + u], c = scr[2 * N + u], d = scr[3 * N + u];
        v[u] = domax ? fmaxf(fmaxf(a, b2), fmaxf(c, d)) : ((a + b2) + (c + d));
    }
}

// ---------------- main fused kernel (r15 + parallel delta_v) ----------------
__global__ __launch_bounds__(256, 3) void sake_all(P p) {
    const bool bf = (p.flag[0] != 0u);
    const int node = blockIdx.x;
    const int i = node & 255;
    const int b = node >> 8;
    const int tid = threadIdx.x;
    const int j = tid;
    const int lane = tid & 63, wv = tid >> 6;
    const int l15 = lane & 15, l4 = lane >> 4;

    __shared__ alignas(16) u16 s_A[256 * 72];
    __shared__ alignas(16) u16 s_wsq[4 * 16 * 72];
    __shared__ alignas(16) u16 s_xs[256 * 4];
    __shared__ alignas(8)  u16 s_sa[256 * 4];
    __shared__ alignas(16) u16 s_att[4 * 272];
    __shared__ alignas(16) float s_rows[3 * 64];   // w1l | be1+lini | h_i
    __shared__ float s_cn[32];
    __shared__ float s_dv[4];
    __shared__ float s_scr[48];
    __shared__ float s_misc[8];

    u16*   s_AT    = s_A;
    float* s_nin   = (float*)s_wsq;
    float* s_t1    = (float*)((char*)s_wsq + 1536);
    float* s_part  = (float*)((char*)s_wsq + 1792);
    float* s_combw = (float*)s_att;

    bf16x8 bw2[2][4];
    #pragma unroll
    for (int n = 0; n < 4; n++)
        #pragma unroll
        for (int ks = 0; ks < 2; ks++)
            bw2[ks][n] = *(const bf16x8*)(p.we2f + ((n * 2 + ks) * 64 + lane) * 8);
    float be2v[4];
    #pragma unroll
    for (int n = 0; n < 4; n++) be2v[n] = p.biasf[B_BE2 + 4 * l15 + n];

    // ---------- P0 ----------
    if (tid < 64) {
        s_rows[tid]       = p.biasf[B_W1L + tid];
        s_rows[64 + tid]  = p.biasf[B_BE1 + tid] + p.lini[node * 64 + tid];
        s_rows[128 + tid] = bf ? bfr(((const u16*)p.h)[node * 64 + tid])
                               : ((const float*)p.h)[node * 64 + tid];
    } else if (tid < 67) {
        s_misc[tid - 64] = p.xf[node * 3 + (tid - 64)];
    } else if (tid == 67) {
        s_misc[3] = p.vsc[node];
    } else if (tid < 72) {
        s_misc[4 + (tid - 68)] = p.biasf[B_GE + (tid - 68)];
    }
    __syncthreads();

    // ---------- P1 ----------
    float nrm;
    {
        float d0 = p.xf[(b * 256 + j) * 3 + 0] - s_misc[0];
        float d1 = p.xf[(b * 256 + j) * 3 + 1] - s_misc[1];
        float d2 = p.xf[(b * 256 + j) * 3 + 2] - s_misc[2];
        nrm = sqrtf(d0 * d0 + d1 * d1 + d2 * d2 + EPSc);
        float den = nrm + EPSc;
        float invd = frcp(den * den);
        uint2 xw;
        xw.x = cvtpk(d0 * invd, d1 * invd);
        xw.y = cvtpk(d2 * invd, nrm);
        *(uint2*)(&s_xs[j * 4]) = xw;

        const f32x4* lj = (const f32x4*)(p.linj + (b * 256 + j) * 64);
        const f32x4* rw = (const f32x4*)(s_rows);       // w1l
        const f32x4* rb = (const f32x4*)(s_rows + 64);  // be1 + lini
        #pragma unroll
        for (int c = 0; c < 8; c++) {
            f32x4 a  = lj[2 * c],  bq = lj[2 * c + 1];
            f32x4 w0 = rw[2 * c],  w1 = rw[2 * c + 1];
            f32x4 b0 = rb[2 * c],  b1 = rb[2 * c + 1];
            float s[8];
            #pragma unroll
            for (int e = 0; e < 4; e++) s[e]     = silu(a[e]  + nrm * w0[e] + b0[e]);
            #pragma unroll
            for (int e = 0; e < 4; e++) s[4 + e] = silu(bq[e] + nrm * w1[e] + b1[e]);
            uint4 w;
            w.x = cvtpk(s[0], s[1]); w.y = cvtpk(s[2], s[3]);
            w.z = cvtpk(s[4], s[5]); w.w = cvtpk(s[6], s[7]);
            *(uint4*)(&s_A[j * 72 + c * 8]) = w;
        }
    }
    WAVE_FENCE();

    // ---------- GEMM1 MFMAs ----------
    f32x4 acc[4][4] = {};
    #pragma unroll
    for (int mt = 0; mt < 4; mt++) {
        int row = (wv * 4 + mt) * 16 + l15;
        #pragma unroll
        for (int ks = 0; ks < 2; ks++) {
            bf16x8 a = *(const bf16x8*)(&s_A[row * 72 + ks * 32 + l4 * 8]);
            #pragma unroll
            for (int n = 0; n < 4; n++)
                acc[mt][n] = __builtin_amdgcn_mfma_f32_16x16x32_bf16(a, bw2[ks][n], acc[mt][n], 0, 0, 0);
        }
    }
    // ---- S4 weight loads issued here (latency hidden under GEMM1 writeback) ----
    bf16x8 bw3[2][5], bw4[2][2];
    #pragma unroll
    for (int n = 0; n < 5; n++)
        #pragma unroll
        for (int ks = 0; ks < 2; ks++)
            bw3[ks][n] = *(const bf16x8*)(p.wc1f + ((n * 2 + ks) * 64 + lane) * 8);
    #pragma unroll
    for (int n = 0; n < 2; n++)
        #pragma unroll
        for (int ks = 0; ks < 2; ks++)
            bw4[ks][n] = *(const bf16x8*)(p.wc2f + ((n * 2 + ks) * 64 + lane) * 8);
    float bc1v[4], bc2v[2];
    #pragma unroll
    for (int n = 0; n < 4; n++) bc1v[n] = p.biasf[B_BC1 + 4 * l15 + n];
    #pragma unroll
    for (int n = 0; n < 2; n++) bc2v[n] = p.biasf[B_BC2 + n * 16 + l15];
    float bsv = p.biasf[B_BS + (l15 & 3)];

    WAVE_FENCE();
    // ---------- GEMM1 writeback ----------
    #pragma unroll
    for (int mt = 0; mt < 4; mt++)
        #pragma unroll
        for (int q = 0; q < 4; q++) {
            int row = (wv * 4 + mt) * 16 + l4 * 4 + q;
            uint2 pk;
            pk.x = cvtpk(silu(acc[mt][0][q] + be2v[0]), silu(acc[mt][1][q] + be2v[1]));
            pk.y = cvtpk(silu(acc[mt][2][q] + be2v[2]), silu(acc[mt][3][q] + be2v[3]));
            *(uint2*)(&s_A[row * 72 + 4 * l15]) = pk;
        }
    WAVE_FENCE();

    // ---------- S4 ----------
    {
        u16* myws = s_wsq + wv * (16 * 72);
        float cmb[2][3] = {};
        #pragma unroll 1
        for (int mt = 0; mt < 4; mt++) {
            f32x4 c1x[5] = {};
            #pragma unroll
            for (int ks = 0; ks < 2; ks++) {
                bf16x8 a = *(const bf16x8*)(&s_A[((wv * 4 + mt) * 16 + l15) * 72 + ks * 32 + l4 * 8]);
                #pragma unroll
                for (int n = 0; n < 5; n++)
                    c1x[n] = __builtin_amdgcn_mfma_f32_16x16x32_bf16(a, bw3[ks][n], c1x[n], 0, 0, 0);
            }
            #pragma unroll
            for (int q = 0; q < 4; q++) {
                uint2 pk;
                pk.x = cvtpk(silu(c1x[0][q] + bc1v[0]), silu(c1x[1][q] + bc1v[1]));
                pk.y = cvtpk(silu(c1x[2][q] + bc1v[2]), silu(c1x[3][q] + bc1v[3]));
                *(uint2*)(&myws[(l4 * 4 + q) * 72 + 4 * l15]) = pk;
            }
            if (l15 < 4) {
                #pragma unroll
                for (int q = 0; q < 4; q++) {
                    int row = wv * 64 + mt * 16 + l4 * 4 + q;
                    float sub = (row == i) ? INFc : 0.f;
                    float lv = lrelu(c1x[4][q] + bsv) - sub;
                    s_sa[row * 4 + l15] = (u16)cvtpk(lv, lv);
                }
            }
            WAVE_FENCE();
            f32x4 co[2] = {};
            #pragma unroll
            for (int ks = 0; ks < 2; ks++) {
                bf16x8 a2 = *(const bf16x8*)(&myws[l15 * 72 + ks * 32 + l4 * 8]);
                #pragma unroll
                for (int n = 0; n < 2; n++)
                    co[n] = __builtin_amdgcn_mfma_f32_16x16x32_bf16(a2, bw4[ks][n], co[n], 0, 0, 0);
            }
            #pragma unroll
            for (int q = 0; q < 4; q++) {
                int r = wv * 64 + mt * 16 + l4 * 4 + q;
                uint2 xw = *(const uint2*)(&s_xs[r * 4]);
                float x0 = __uint_as_float(xw.x << 16);
                float x1 = __uint_as_float(xw.x & 0xffff0000u);
                float x2 = __uint_as_float(xw.y << 16);
                #pragma unroll
                for (int n = 0; n < 2; n++) {
                    float c = co[n][q] + bc2v[n];
                    cmb[n][0] += c * x0;
                    cmb[n][1] += c * x1;
                    cmb[n][2] += c * x2;
                }
            }
        }
        #pragma unroll
        for (int n = 0; n < 2; n++)
            #pragma unroll
            for (int k = 0; k < 3; k++) {
                float v = cmb[n][k];
                v += __shfl_xor(v, 16);
                v += __shfl_xor(v, 32);
                cmb[n][k] = v;
            }
        if (l4 == 0) {
            #pragma unroll
            for (int n = 0; n < 2; n++)
                #pragma unroll
                for (int k = 0; k < 3; k++)
                    s_combw[(wv * 32 + n * 16 + l15) * 3 + k] = cmb[n][k];
        }
    }
    __syncthreads();

    // ---------- S5: read he rows + comb_norm (wave0 lanes 0-31) / delta_v (wave1, parallel) ----------
    uint4 her[8];
    #pragma unroll
    for (int c = 0; c < 8; c++) her[c] = *(const uint4*)(&s_A[j * 72 + c * 8]);
    float cnv = 0.f, dva = 0.f, dvb = 0.f, dvc = 0.f;
    if (tid < 32) {
        float c0 = 0.f, c1 = 0.f, c2 = 0.f;
        #pragma unroll
        for (int w = 0; w < 4; w++) {
            c0 += s_combw[(w * 32 + tid) * 3 + 0];
            c1 += s_combw[(w * 32 + tid) * 3 + 1];
            c2 += s_combw[(w * 32 + tid) * 3 + 2];
        }
        cnv = c0 * c0 + c1 * c1 + c2 * c2;
    } else if (wv == 1) {
        // delta_v: 64 lanes, each reads 2 (w,c)-pairs x 3 channels, then wave-reduce
        #pragma unroll
        for (int r = 0; r < 2; r++) {
            int pp = lane + r * 64;
            dva += s_combw[pp * 3 + 0];
            dvb += s_combw[pp * 3 + 1];
            dvc += s_combw[pp * 3 + 2];
        }
        #pragma unroll
        for (int o = 32; o; o >>= 1) {
            dva += __shfl_xor(dva, o);
            dvb += __shfl_xor(dvb, o);
            dvc += __shfl_xor(dvc, o);
        }
    }
    __syncthreads();

    // ---------- S6 ----------
    #pragma unroll
    for (int c = 0; c < 8; c++) {
        u32 d[4] = { her[c].x, her[c].y, her[c].z, her[c].w };
        #pragma unroll
        for (int dw = 0; dw < 4; dw++) {
            int hh = c * 8 + dw * 2;
            s_AT[hh * 272 + j]       = (u16)(d[dw] & 0xffffu);
            s_AT[(hh + 1) * 272 + j] = (u16)(d[dw] >> 16);
        }
    }
    if (tid < 32) s_cn[tid] = cnv;
    else if (wv == 1 && lane < 3) {
        float sel = (lane == 0) ? dva : (lane == 1) ? dvb : dvc;
        s_dv[lane] = sel * (1.0f / 8192.f);
    }

    // ---------- P7: softmaxes (2 reductions) ----------
    {
        float pen = (j == i) ? INFc : 0.f;
        float elb = -(nrm + pen);
        float ge[4] = { s_misc[4], s_misc[5], s_misc[6], s_misc[7] };
        float sl[4];
        #pragma unroll
        for (int u = 0; u < 4; u++) sl[u] = bfr(s_sa[j * 4 + u]);

        float ae[4], as_[4];
        #pragma unroll
        for (int u = 0; u < 4; u++) ae[u] = __expf(ge[u] * elb);
        #pragma unroll
        for (int u = 0; u < 4; u++) as_[u] = __expf(sl[u]);   // |sl| bounded; diag -1e5 -> 0

        float r8[8] = { ae[0], ae[1], ae[2], ae[3], as_[0], as_[1], as_[2], as_[3] };
        blk_red<8>(r8, false, s_scr, tid);

        float ep[4];
        #pragma unroll
        for (int u = 0; u < 4; u++)
            ep[u] = __expf(ae[u] * frcp(r8[u]) * as_[u] * frcp(r8[4 + u]));
        float r4b[4] = { ep[0], ep[1], ep[2], ep[3] };
        blk_red<4>(r4b, false, s_scr + 32, tid);
        #pragma unroll
        for (int u = 0; u < 4; u++) {
            float av = ep[u] * frcp(r4b[u]);
            s_att[u * 272 + j] = (u16)cvtpk(av, av);
        }
    }
    __syncthreads();

    // ---------- P8 ----------
    {
        f32x4 hg = {};
        #pragma unroll
        for (int ks = 0; ks < 8; ks++) {
            bf16x8 af = *(const bf16x8*)(&s_AT[(wv * 16 + l15) * 272 + ks * 32 + l4 * 8]);
            bf16x8 bfv = *(const bf16x8*)(&s_att[(l15 & 3) * 272 + ks * 32 + l4 * 8]);
            hg = __builtin_amdgcn_mfma_f32_16x16x32_bf16(af, bfv, hg, 0, 0, 0);
        }
        if (l15 < 4) {
            #pragma unroll
            for (int q = 0; q < 4; q++)
                s_nin[64 + (wv * 16 + l4 * 4 + q) * 4 + l15] = hg[q];
        }
    }
    if (wv == 0) {
        float a[4] = {};
        #pragma unroll
        for (int e = 0; e < 8; e++) {
            int c = l4 * 8 + e;
            f32x4 w4 = *(const f32x4*)(p.wp1c + c * 64 + 4 * l15);
            float cv = s_cn[c];
            #pragma unroll
            for (int n = 0; n < 4; n++) a[n] += cv * w4[n];
        }
        #pragma unroll
        for (int n = 0; n < 4; n++) {
            a[n] += __shfl_xor(a[n], 16);
            a[n] += __shfl_xor(a[n], 32);
        }
        if (l4 == 0) {
            f32x4 tv;
            #pragma unroll
            for (int n = 0; n < 4; n++) tv[n] = silu(a[n] + p.biasf[B_BP1 + 4 * l15 + n]);
            *(f32x4*)(&s_t1[4 * l15]) = tv;
        }
    } else if (wv == 1) {
        s_nin[lane] = s_rows[128 + lane];
    }
    __syncthreads();

    // ---------- P9 ----------
    if (wv == 2) {
        float a[4] = {};
        #pragma unroll
        for (int it = 0; it < 16; it++) {
            int k = l4 * 16 + it;
            f32x4 w4 = *(const f32x4*)(p.wp2c + k * 64 + 4 * l15);
            float tk = s_t1[k];
            #pragma unroll
            for (int n = 0; n < 4; n++) a[n] += tk * w4[n];
        }
        #pragma unroll
        for (int n = 0; n < 4; n++) {
            a[n] += __shfl_xor(a[n], 16);
            a[n] += __shfl_xor(a[n], 32);
        }
        if (l4 == 0) {
            f32x4 hv;
            #pragma unroll
            for (int n = 0; n < 4; n++) hv[n] = a[n] + p.biasf[B_BP2 + 4 * l15 + n];
            *(f32x4*)(&s_nin[320 + 4 * l15]) = hv;
        }
        WAVE_FENCE();
    }
    {
        const int Q = (wv == 0) ? 0 : (wv == 1) ? 96 : (wv == 2) ? 288 : 192;
        int k0 = Q + l4 * 24;
        float a[4] = {};
        #pragma unroll
        for (int it = 0; it < 6; it++) {
            f32x4 inv = *(const f32x4*)(&s_nin[k0 + it * 4]);
            #pragma unroll
            for (int r = 0; r < 4; r++) {
                f32x4 w4 = *(const f32x4*)(p.wn1c + (k0 + it * 4 + r) * 64 + 4 * l15);
                #pragma unroll
                for (int n = 0; n < 4; n++) a[n] += inv[r] * w4[n];
            }
        }
        #pragma unroll
        for (int n = 0; n < 4; n++) {
            a[n] += __shfl_xor(a[n], 16);
            a[n] += __shfl_xor(a[n], 32);
        }
        if (l4 == 0) {
            f32x4 pv = { a[0], a[1], a[2], a[3] };
            *(f32x4*)(&s_part[wv * 64 + 4 * l15]) = pv;
        }
    }
    __syncthreads();

    // ---------- P10 ----------
    if (wv == 0) {
        float v2 = p.biasf[B_BN1 + lane] + (s_part[lane] + s_part[64 + lane])
                 + (s_part[128 + lane] + s_part[192 + lane]);
        s_t1[lane] = silu(v2);
        WAVE_FENCE();
        float a[4] = {};
        #pragma unroll
        for (int it = 0; it < 16; it++) {
            int k = l4 * 16 + it;
            f32x4 w4 = *(const f32x4*)(p.wn2c + k * 64 + 4 * l15);
            float tk = s_t1[k];
            #pragma unroll
            for (int n = 0; n < 4; n++) a[n] += tk * w4[n];
        }
        #pragma unroll
        for (int n = 0; n < 4; n++) {
            a[n] += __shfl_xor(a[n], 16);
            a[n] += __shfl_xor(a[n], 32);
        }
        if (l4 == 0) {
            float o[4];
            #pragma unroll
            for (int n = 0; n < 4; n++) {
                int oo = 4 * l15 + n;
                o[n] = s_rows[128 + oo] + p.biasf[B_BN2 + oo] + a[n];
            }
            if (bf) {
                uint2 w; w.x = cvtpk(o[0], o[1]); w.y = cvtpk(o[2], o[3]);
                *(uint2*)((u16*)p.out + node * 64 + 4 * l15) = w;
            } else {
                f32x4 w = { o[0], o[1], o[2], o[3] };
                *(f32x4*)((float*)p.out + node * 64 + 4 * l15) = w;
            }
        }
    } else if (wv == 1 && lane < 3) {
        int k = lane;
        float vn = s_dv[k] + s_misc[3] * p.vf[node * 3 + k];
        float xn = p.xf[node * 3 + k] + vn;
        STr(p.out, 65536 + node * 3 + k, xn, bf);
        STr(p.out, 68608 + node * 3 + k, vn, bf);
    }
}

extern "C" void kernel_launch(void* const* d_in, const int* in_sizes, int n_in,
                              void* d_out, int out_size, void* d_ws, size_t ws_size,
                              hipStream_t stream) {
    (void)in_sizes; (void)n_in; (void)out_size; (void)ws_size;
    char* ws = (char*)d_ws;

    P p;
    p.h   = d_in[0];  p.x   = d_in[1];  p.v   = d_in[2];
    p.We1 = d_in[3];  p.be1 = d_in[4];  p.We2 = d_in[5];  p.be2 = d_in[6];
    p.Wc1 = d_in[7];  p.bc1 = d_in[8];  p.Wc2 = d_in[9];  p.bc2 = d_in[10];
    p.Wp1 = d_in[11]; p.bp1 = d_in[12]; p.Wp2 = d_in[13]; p.bp2 = d_in[14];
    p.Ws_ = d_in[15]; p.bs_ = d_in[16];
    p.Wn1 = d_in[17]; p.bn1 = d_in[18]; p.Wn2 = d_in[19]; p.bn2 = d_in[20];
    p.Wv1 = d_in[21]; p.bv1 = d_in[22]; p.Wv2 = d_in[23]; p.lg  = d_in[24];
    p.linj  = (float*)(ws + O_LINJ);
    p.lini  = (float*)(ws + O_LINI);
    p.vsc   = (float*)(ws + O_VSC);
    p.wp1c  = (float*)(ws + O_WP1C);
    p.wp2c  = (float*)(ws + O_WP2C);
    p.wn1c  = (float*)(ws + O_WN1C);
    p.wn2c  = (float*)(ws + O_WN2C);
    p.xf    = (float*)(ws + O_XF);
    p.vf    = (float*)(ws + O_VF);
    p.biasf = (float*)(ws + O_BIAS);
    p.we2f  = (u16*)(ws + O_WE2F);
    p.wc1f  = (u16*)(ws + O_WC1F);
    p.wc2f  = (u16*)(ws + O_WC2F);
    p.flagw = (u32*)(ws + O_FLAG);
    p.flag  = (const u32*)(ws + O_FLAG);
    p.out   = d_out;

    hipLaunchKernelGGL(prep_all, dim3(26), dim3(256), 0, stream, p);
    hipLaunchKernelGGL(sake_all, dim3(1024), dim3(256), 0, stream, p);
}

// Round 17
// 48.327 us; speedup vs baseline: 5.6529x; 1.0132x over previous
//
#include <hip/hip_runtime.h>

typedef unsigned short u16;
typedef unsigned int   u32;
typedef __attribute__((ext_vector_type(8))) short bf16x8;
typedef __attribute__((ext_vector_type(4))) float f32x4;

#define EPSc 1e-5f
#define INFc 1e5f

// ---------------- ws byte offsets ----------------
#define O_LINJ  0         // f32[1024][64]
#define O_LINI  262144    // f32[1024][64]
#define O_VSC   524288    // f32[1024]
#define O_WE2F  528384    // u16[4*2*64*8]  (cols permuted: c = 4*l15+n)
#define O_WC1F  536576    // u16[5*2*64*8]  (n<4 permuted; tile4 = Ws|0)
#define O_WC2F  546816    // u16[2*2*64*8]  (natural)
#define O_WP1C  550912    // f32[32][64]
#define O_WP2C  559104    // f32[64][64]
#define O_WN2C  575488    // f32[64][64]
#define O_WN1C  591872    // f32[384][64]
#define O_XF    690176    // f32[1024*3]
#define O_VF    702464    // f32[1024*3]
#define O_BIAS  714752    // f32[552]
#define O_FLAG  741536    // u32

// biasf float indices
#define B_BE2 0
#define B_BC1 64
#define B_BC2 128
#define B_BS  160
#define B_GE  164
#define B_BP1 168
#define B_BP2 232
#define B_BN1 296
#define B_BN2 360
#define B_W1L 424
#define B_BE1 488

struct P {
    const void *h, *x, *v;
    const void *We1, *be1, *We2, *be2, *Wc1, *bc1, *Wc2, *bc2;
    const void *Wp1, *bp1, *Wp2, *bp2, *Ws_, *bs_;
    const void *Wn1, *bn1, *Wn2, *bn2, *Wv1, *bv1, *Wv2, *lg;
    float *linj, *lini, *vsc, *wp1c, *wp2c, *wn1c, *wn2c, *xf, *vf, *biasf;
    u16 *we2f, *wc1f, *wc2f;
    u32 *flagw;
    const u32 *flag;
    void *out;
};

__device__ __forceinline__ float bfr(u16 u) { return __uint_as_float(((u32)u) << 16); }
__device__ __forceinline__ u16 f2bf(float f) {
    u32 u = __float_as_uint(f);
    u = u + 0x7fffu + ((u >> 16) & 1u);
    return (u16)(u >> 16);
}
__device__ __forceinline__ u32 cvtpk(float lo, float hi) {
    u32 r;
    asm("v_cvt_pk_bf16_f32 %0, %1, %2" : "=v"(r) : "v"(lo), "v"(hi));
    return r;
}
__device__ __forceinline__ float frcp(float x) { return __builtin_amdgcn_rcpf(x); }
__device__ __forceinline__ float silu(float x) { return x * frcp(1.f + __expf(-x)); }
__device__ __forceinline__ float lrelu(float x) { return x > 0.f ? x : 0.2f * x; }

__device__ __forceinline__ float LDr(const void* p, int i, bool bf) {
    return bf ? bfr(((const u16*)p)[i]) : ((const float*)p)[i];
}
__device__ __forceinline__ u16 ENCr(const void* p, int i, bool bf) {
    return bf ? ((const u16*)p)[i] : f2bf(((const float*)p)[i]);
}
__device__ __forceinline__ void STr(void* p, int i, float v, bool bf) {
    if (bf) ((u16*)p)[i] = (u16)cvtpk(v, v);
    else    ((float*)p)[i] = v;
}
#define WAVE_FENCE() do { asm volatile("s_waitcnt lgkmcnt(0)" ::: "memory"); \
                          __builtin_amdgcn_sched_barrier(0); } while (0)

// per-block inline dtype detect (pure function of h)
__device__ __forceinline__ bool block_flag(const void* h, u32* s_flagv, int t) {
    if (t < 64) {
        const u16* ph = (const u16*)h;
        int cnt = 0;
        #pragma unroll
        for (int e = 0; e < 4; e++) {
            float v = bfr(ph[t * 4 + e]);
            float a = fabsf(v);
            if (v == 0.f || (a > 1e-6f && a < 1024.f)) cnt++;
        }
        #pragma unroll
        for (int o = 32; o; o >>= 1) cnt += __shfl_xor(cnt, o);
        if (t == 0) *s_flagv = (cnt >= 224) ? 1u : 0u;
    }
    __syncthreads();
    return *s_flagv != 0u;
}

// ---------------- merged prep: 26 blocks (r16, unchanged) ----------------
__global__ __launch_bounds__(256) void prep_all(P p) {
    __shared__ u32 s_flagv;
    const int t = threadIdx.x;
    const int blk = blockIdx.x;
    const bool bf = block_flag(p.h, &s_flagv, t);

    if (blk == 0) {
        if (t == 0) p.flagw[0] = bf ? 1u : 0u;
        for (int idx = t; idx < 4096; idx += 256) {
            int e = idx & 7, l = (idx >> 3) & 63, ks = (idx >> 9) & 1, nt = idx >> 10;
            int k = ks * 32 + (l >> 4) * 8 + e, c = (l & 15) * 4 + nt;
            p.we2f[idx] = ENCr(p.We2, k * 64 + c, bf);
        }
    } else if (blk == 1) {
        for (int idx = t; idx < 5120; idx += 256) {
            int e = idx & 7, l = (idx >> 3) & 63, ks = (idx >> 9) & 1, nt = idx >> 10;
            int k = ks * 32 + (l >> 4) * 8 + e;
            u16 v;
            if (nt < 4) v = ENCr(p.Wc1, k * 64 + (l & 15) * 4 + nt, bf);
            else { int cc = l & 15; v = (cc < 4) ? ENCr(p.Ws_, k * 4 + cc, bf) : (u16)0; }
            p.wc1f[idx] = v;
        }
    } else if (blk == 2) {
        for (int idx = t; idx < 2048; idx += 256) {
            int e = idx & 7, l = (idx >> 3) & 63, ks = (idx >> 9) & 1, nt = idx >> 10;
            int k = ks * 32 + (l >> 4) * 8 + e, c = nt * 16 + (l & 15);
            p.wc2f[idx] = ENCr(p.Wc2, k * 32 + c, bf);
        }
        if (t < 64) {
            p.biasf[B_BE2 + t] = LDr(p.be2, t, bf);
            p.biasf[B_BC1 + t] = LDr(p.bc1, t, bf);
            p.biasf[B_BP1 + t] = LDr(p.bp1, t, bf);
            p.biasf[B_BP2 + t] = LDr(p.bp2, t, bf);
            p.biasf[B_BN1 + t] = LDr(p.bn1, t, bf);
            p.biasf[B_BN2 + t] = LDr(p.bn2, t, bf);
            p.biasf[B_W1L + t] = LDr(p.We1, 128 * 64 + t, bf);
            p.biasf[B_BE1 + t] = LDr(p.be1, t, bf);
        } else if (t < 96) {
            p.biasf[B_BC2 + (t - 64)] = LDr(p.bc2, t - 64, bf);
        } else if (t < 100) {
            p.biasf[B_BS + (t - 96)] = LDr(p.bs_, t - 96, bf);
            p.biasf[B_GE + (t - 96)] = __expf(LDr(p.lg, t - 96, bf));
        }
    } else if (blk == 3) {
        for (int i = t; i < 3072; i += 256) {
            p.xf[i] = LDr(p.x, i, bf);
            p.vf[i] = LDr(p.v, i, bf);
        }
    } else if (blk == 4) {
        for (int idx = t; idx < 2048; idx += 256) p.wp1c[idx] = LDr(p.Wp1, idx, bf);
        for (int idx = t; idx < 4096; idx += 256) p.wp2c[idx] = LDr(p.Wp2, idx, bf);
    } else if (blk == 5) {
        for (int idx = t; idx < 4096; idx += 256) p.wn2c[idx] = LDr(p.Wn2, idx, bf);
    } else if (blk < 10) {
        int base = (blk - 6) * 6144;
        for (int idx = t; idx < 6144; idx += 256) p.wn1c[base + idx] = LDr(p.Wn1, base + idx, bf);
    } else {
        // node blocks (16): 4 waves x 16 nodes; raw weights staged in LDS
        __shared__ alignas(16) u16 lds_wj[4096];
        __shared__ alignas(16) u16 lds_wi[4096];
        __shared__ alignas(16) u16 lds_wv[4096];
        __shared__ alignas(16) u16 shh[4][16 * 72];
        for (int idx = t; idx < 4096; idx += 256) {
            lds_wj[idx] = ENCr(p.We1, idx, bf);
            lds_wi[idx] = ENCr(p.We1, 4096 + idx, bf);
            lds_wv[idx] = ENCr(p.Wv1, idx, bf);
        }
        const int w = t >> 6, lane = t & 63;
        const int l15 = lane & 15, l4 = lane >> 4;
        const int n0 = (blk - 10) * 64 + w * 16;
        #pragma unroll
        for (int rr = 0; rr < 4; rr++) {
            int row = rr * 4 + l4;
            if (bf) {
                const u16* hb = (const u16*)p.h;
                *(uint2*)(&shh[w][row * 72 + l15 * 4]) =
                    *(const uint2*)(&hb[(n0 + row) * 64 + l15 * 4]);
            } else {
                const float* hf = (const float*)p.h;
                f32x4 hv = *(const f32x4*)(&hf[(n0 + row) * 64 + l15 * 4]);
                uint2 ww; ww.x = cvtpk(hv[0], hv[1]); ww.y = cvtpk(hv[2], hv[3]);
                *(uint2*)(&shh[w][row * 72 + l15 * 4]) = ww;
            }
        }
        __syncthreads();
        f32x4 dj[4] = {}, di[4] = {}, dv[4] = {};
        #pragma unroll
        for (int nt = 0; nt < 4; nt++) {
            #pragma unroll
            for (int ks = 0; ks < 2; ks++) {
                bf16x8 a = *(const bf16x8*)(&shh[w][l15 * 72 + ks * 32 + l4 * 8]);
                bf16x8 bj, bi2, bvv;
                #pragma unroll
                for (int e = 0; e < 8; e++) {
                    int off = (ks * 32 + l4 * 8 + e) * 64 + nt * 16 + l15;
                    bj[e]  = (short)lds_wj[off];
                    bi2[e] = (short)lds_wi[off];
                    bvv[e] = (short)lds_wv[off];
                }
                dj[nt] = __builtin_amdgcn_mfma_f32_16x16x32_bf16(a, bj,  dj[nt], 0, 0, 0);
                di[nt] = __builtin_amdgcn_mfma_f32_16x16x32_bf16(a, bi2, di[nt], 0, 0, 0);
                dv[nt] = __builtin_amdgcn_mfma_f32_16x16x32_bf16(a, bvv, dv[nt], 0, 0, 0);
            }
        }
        #pragma unroll
        for (int nt = 0; nt < 4; nt++)
            #pragma unroll
            for (int q = 0; q < 4; q++) {
                int n = n0 + l4 * 4 + q, c = nt * 16 + l15;
                p.linj[n * 64 + c] = dj[nt][q];
                p.lini[n * 64 + c] = di[nt][q];
            }
        float bv1v[4], wv2v[4];
        #pragma unroll
        for (int nt = 0; nt < 4; nt++) {
            bv1v[nt] = LDr(p.bv1, nt * 16 + l15, bf);
            wv2v[nt] = LDr(p.Wv2, nt * 16 + l15, bf);
        }
        #pragma unroll
        for (int q = 0; q < 4; q++) {
            float s = 0.f;
            #pragma unroll
            for (int nt = 0; nt < 4; nt++)
                s += silu(dv[nt][q] + bv1v[nt]) * wv2v[nt];
            s += __shfl_xor(s, 1);
            s += __shfl_xor(s, 2);
            s += __shfl_xor(s, 4);
            s += __shfl_xor(s, 8);
            if (l15 == 0) p.vsc[n0 + l4 * 4 + q] = s;
        }
    }
}

// N-channel block reduction, 256 threads
template<int N>
__device__ __forceinline__ void blk_red(float v[N], bool domax, float* scr, int tid) {
    #pragma unroll
    for (int s2 = 32; s2; s2 >>= 1)
        #pragma unroll
        for (int u = 0; u < N; u++) {
            float o = __shfl_xor(v[u], s2);
            v[u] = domax ? fmaxf(v[u], o) : (v[u] + o);
        }
    if ((tid & 63) == 0) {
        int w = tid >> 6;
        #pragma unroll
        for (int u = 0; u < N; u++) scr[w * N + u] = v[u];
    }
    __syncthreads();
    #pragma unroll
    for (int u = 0; u < N; u++) {
        float a = scr[0 * N + u], b2 = scr[1 * N + u], c = scr[2 * N + u], d = scr[3 * N + u];
        v[u] = domax ? fmaxf(fmaxf(a, b2), fmaxf(c, d)) : ((a + b2) + (c + d));
    }
}

// ---------------- main fused kernel (r16 + transpose-free heagg) ----------------
__global__ __launch_bounds__(256, 3) void sake_all(P p) {
    const bool bf = (p.flag[0] != 0u);
    const int node = blockIdx.x;
    const int i = node & 255;
    const int b = node >> 8;
    const int tid = threadIdx.x;
    const int j = tid;
    const int lane = tid & 63, wv = tid >> 6;
    const int l15 = lane & 15, l4 = lane >> 4;

    __shared__ alignas(16) u16 s_A[256 * 72];      // spre -> he (stays row-major to the end)
    __shared__ alignas(16) u16 s_wsq[4 * 16 * 72];
    __shared__ alignas(16) u16 s_xs[256 * 4];
    __shared__ alignas(8)  u16 s_sa[256 * 4];
    __shared__ alignas(16) u16 s_att[4 * 272];
    __shared__ alignas(16) float s_rows[3 * 64];   // w1l | be1+lini | h_i
    __shared__ float s_cn[32];
    __shared__ float s_dv[4];
    __shared__ float s_scr[48];
    __shared__ float s_misc[8];

    float* s_nin   = (float*)s_wsq;
    float* s_t1    = (float*)((char*)s_wsq + 1536);
    float* s_part  = (float*)((char*)s_wsq + 1792);
    float* s_combw = (float*)s_att;

    bf16x8 bw2[2][4];
    #pragma unroll
    for (int n = 0; n < 4; n++)
        #pragma unroll
        for (int ks = 0; ks < 2; ks++)
            bw2[ks][n] = *(const bf16x8*)(p.we2f + ((n * 2 + ks) * 64 + lane) * 8);
    float be2v[4];
    #pragma unroll
    for (int n = 0; n < 4; n++) be2v[n] = p.biasf[B_BE2 + 4 * l15 + n];

    // ---------- P0 ----------
    if (tid < 64) {
        s_rows[tid]       = p.biasf[B_W1L + tid];
        s_rows[64 + tid]  = p.biasf[B_BE1 + tid] + p.lini[node * 64 + tid];
        s_rows[128 + tid] = bf ? bfr(((const u16*)p.h)[node * 64 + tid])
                               : ((const float*)p.h)[node * 64 + tid];
    } else if (tid < 67) {
        s_misc[tid - 64] = p.xf[node * 3 + (tid - 64)];
    } else if (tid == 67) {
        s_misc[3] = p.vsc[node];
    } else if (tid < 72) {
        s_misc[4 + (tid - 68)] = p.biasf[B_GE + (tid - 68)];
    }
    __syncthreads();

    // ---------- P1 ----------
    float nrm;
    {
        float d0 = p.xf[(b * 256 + j) * 3 + 0] - s_misc[0];
        float d1 = p.xf[(b * 256 + j) * 3 + 1] - s_misc[1];
        float d2 = p.xf[(b * 256 + j) * 3 + 2] - s_misc[2];
        nrm = sqrtf(d0 * d0 + d1 * d1 + d2 * d2 + EPSc);
        float den = nrm + EPSc;
        float invd = frcp(den * den);
        uint2 xw;
        xw.x = cvtpk(d0 * invd, d1 * invd);
        xw.y = cvtpk(d2 * invd, nrm);
        *(uint2*)(&s_xs[j * 4]) = xw;

        const f32x4* lj = (const f32x4*)(p.linj + (b * 256 + j) * 64);
        const f32x4* rw = (const f32x4*)(s_rows);       // w1l
        const f32x4* rb = (const f32x4*)(s_rows + 64);  // be1 + lini
        #pragma unroll
        for (int c = 0; c < 8; c++) {
            f32x4 a  = lj[2 * c],  bq = lj[2 * c + 1];
            f32x4 w0 = rw[2 * c],  w1 = rw[2 * c + 1];
            f32x4 b0 = rb[2 * c],  b1 = rb[2 * c + 1];
            float s[8];
            #pragma unroll
            for (int e = 0; e < 4; e++) s[e]     = silu(a[e]  + nrm * w0[e] + b0[e]);
            #pragma unroll
            for (int e = 0; e < 4; e++) s[4 + e] = silu(bq[e] + nrm * w1[e] + b1[e]);
            uint4 w;
            w.x = cvtpk(s[0], s[1]); w.y = cvtpk(s[2], s[3]);
            w.z = cvtpk(s[4], s[5]); w.w = cvtpk(s[6], s[7]);
            *(uint4*)(&s_A[j * 72 + c * 8]) = w;
        }
    }
    WAVE_FENCE();

    // ---------- GEMM1 MFMAs ----------
    f32x4 acc[4][4] = {};
    #pragma unroll
    for (int mt = 0; mt < 4; mt++) {
        int row = (wv * 4 + mt) * 16 + l15;
        #pragma unroll
        for (int ks = 0; ks < 2; ks++) {
            bf16x8 a = *(const bf16x8*)(&s_A[row * 72 + ks * 32 + l4 * 8]);
            #pragma unroll
            for (int n = 0; n < 4; n++)
                acc[mt][n] = __builtin_amdgcn_mfma_f32_16x16x32_bf16(a, bw2[ks][n], acc[mt][n], 0, 0, 0);
        }
    }
    // ---- S4 weight loads issued here (latency hidden under GEMM1 writeback) ----
    bf16x8 bw3[2][5], bw4[2][2];
    #pragma unroll
    for (int n = 0; n < 5; n++)
        #pragma unroll
        for (int ks = 0; ks < 2; ks++)
            bw3[ks][n] = *(const bf16x8*)(p.wc1f + ((n * 2 + ks) * 64 + lane) * 8);
    #pragma unroll
    for (int n = 0; n < 2; n++)
        #pragma unroll
        for (int ks = 0; ks < 2; ks++)
            bw4[ks][n] = *(const bf16x8*)(p.wc2f + ((n * 2 + ks) * 64 + lane) * 8);
    float bc1v[4], bc2v[2];
    #pragma unroll
    for (int n = 0; n < 4; n++) bc1v[n] = p.biasf[B_BC1 + 4 * l15 + n];
    #pragma unroll
    for (int n = 0; n < 2; n++) bc2v[n] = p.biasf[B_BC2 + n * 16 + l15];
    float bsv = p.biasf[B_BS + (l15 & 3)];

    WAVE_FENCE();
    // ---------- GEMM1 writeback ----------
    #pragma unroll
    for (int mt = 0; mt < 4; mt++)
        #pragma unroll
        for (int q = 0; q < 4; q++) {
            int row = (wv * 4 + mt) * 16 + l4 * 4 + q;
            uint2 pk;
            pk.x = cvtpk(silu(acc[mt][0][q] + be2v[0]), silu(acc[mt][1][q] + be2v[1]));
            pk.y = cvtpk(silu(acc[mt][2][q] + be2v[2]), silu(acc[mt][3][q] + be2v[3]));
            *(uint2*)(&s_A[row * 72 + 4 * l15]) = pk;
        }
    WAVE_FENCE();

    // ---------- S4 ----------
    {
        u16* myws = s_wsq + wv * (16 * 72);
        float cmb[2][3] = {};
        #pragma unroll 1
        for (int mt = 0; mt < 4; mt++) {
            f32x4 c1x[5] = {};
            #pragma unroll
            for (int ks = 0; ks < 2; ks++) {
                bf16x8 a = *(const bf16x8*)(&s_A[((wv * 4 + mt) * 16 + l15) * 72 + ks * 32 + l4 * 8]);
                #pragma unroll
                for (int n = 0; n < 5; n++)
                    c1x[n] = __builtin_amdgcn_mfma_f32_16x16x32_bf16(a, bw3[ks][n], c1x[n], 0, 0, 0);
            }
            #pragma unroll
            for (int q = 0; q < 4; q++) {
                uint2 pk;
                pk.x = cvtpk(silu(c1x[0][q] + bc1v[0]), silu(c1x[1][q] + bc1v[1]));
                pk.y = cvtpk(silu(c1x[2][q] + bc1v[2]), silu(c1x[3][q] + bc1v[3]));
                *(uint2*)(&myws[(l4 * 4 + q) * 72 + 4 * l15]) = pk;
            }
            if (l15 < 4) {
                #pragma unroll
                for (int q = 0; q < 4; q++) {
                    int row = wv * 64 + mt * 16 + l4 * 4 + q;
                    float sub = (row == i) ? INFc : 0.f;
                    float lv = lrelu(c1x[4][q] + bsv) - sub;
                    s_sa[row * 4 + l15] = (u16)cvtpk(lv, lv);
                }
            }
            WAVE_FENCE();
            f32x4 co[2] = {};
            #pragma unroll
            for (int ks = 0; ks < 2; ks++) {
                bf16x8 a2 = *(const bf16x8*)(&myws[l15 * 72 + ks * 32 + l4 * 8]);
                #pragma unroll
                for (int n = 0; n < 2; n++)
                    co[n] = __builtin_amdgcn_mfma_f32_16x16x32_bf16(a2, bw4[ks][n], co[n], 0, 0, 0);
            }
            #pragma unroll
            for (int q = 0; q < 4; q++) {
                int r = wv * 64 + mt * 16 + l4 * 4 + q;
                uint2 xw = *(const uint2*)(&s_xs[r * 4]);
                float x0 = __uint_as_float(xw.x << 16);
                float x1 = __uint_as_float(xw.x & 0xffff0000u);
                float x2 = __uint_as_float(xw.y << 16);
                #pragma unroll
                for (int n = 0; n < 2; n++) {
                    float c = co[n][q] + bc2v[n];
                    cmb[n][0] += c * x0;
                    cmb[n][1] += c * x1;
                    cmb[n][2] += c * x2;
                }
            }
        }
        #pragma unroll
        for (int n = 0; n < 2; n++)
            #pragma unroll
            for (int k = 0; k < 3; k++) {
                float v = cmb[n][k];
                v += __shfl_xor(v, 16);
                v += __shfl_xor(v, 32);
                cmb[n][k] = v;
            }
        if (l4 == 0) {
            #pragma unroll
            for (int n = 0; n < 2; n++)
                #pragma unroll
                for (int k = 0; k < 3; k++)
                    s_combw[(wv * 32 + n * 16 + l15) * 3 + k] = cmb[n][k];
        }
    }
    __syncthreads();   // B2: combw + he + sa all visible

    // ---------- S5: comb_norm (lanes 0-31) / delta_v (wave1) ; stores to s_cn/s_dv ----------
    // combw reads finish before P7's att writes overwrite the alias: the two blk_red
    // internal __syncthreads in P7 order them.
    if (tid < 32) {
        float c0 = 0.f, c1 = 0.f, c2 = 0.f;
        #pragma unroll
        for (int w = 0; w < 4; w++) {
            c0 += s_combw[(w * 32 + tid) * 3 + 0];
            c1 += s_combw[(w * 32 + tid) * 3 + 1];
            c2 += s_combw[(w * 32 + tid) * 3 + 2];
        }
        s_cn[tid] = c0 * c0 + c1 * c1 + c2 * c2;
    } else if (wv == 1) {
        float dva = 0.f, dvb = 0.f, dvc = 0.f;
        #pragma unroll
        for (int r = 0; r < 2; r++) {
            int pp = lane + r * 64;
            dva += s_combw[pp * 3 + 0];
            dvb += s_combw[pp * 3 + 1];
            dvc += s_combw[pp * 3 + 2];
        }
        #pragma unroll
        for (int o = 32; o; o >>= 1) {
            dva += __shfl_xor(dva, o);
            dvb += __shfl_xor(dvb, o);
            dvc += __shfl_xor(dvc, o);
        }
        if (lane < 3) {
            float sel = (lane == 0) ? dva : (lane == 1) ? dvb : dvc;
            s_dv[lane] = sel * (1.0f / 8192.f);
        }
    }

    // ---------- P7: softmaxes (2 reductions) ----------
    {
        float pen = (j == i) ? INFc : 0.f;
        float elb = -(nrm + pen);
        float ge[4] = { s_misc[4], s_misc[5], s_misc[6], s_misc[7] };
        float sl[4];
        #pragma unroll
        for (int u = 0; u < 4; u++) sl[u] = bfr(s_sa[j * 4 + u]);

        float ae[4], as_[4];
        #pragma unroll
        for (int u = 0; u < 4; u++) ae[u] = __expf(ge[u] * elb);
        #pragma unroll
        for (int u = 0; u < 4; u++) as_[u] = __expf(sl[u]);   // |sl| bounded; diag -1e5 -> 0

        float r8[8] = { ae[0], ae[1], ae[2], ae[3], as_[0], as_[1], as_[2], as_[3] };
        blk_red<8>(r8, false, s_scr, tid);      // internal syncthreads: orders combw reads vs att writes

        float ep[4];
        #pragma unroll
        for (int u = 0; u < 4; u++)
            ep[u] = __expf(ae[u] * frcp(r8[u]) * as_[u] * frcp(r8[4 + u]));
        float r4b[4] = { ep[0], ep[1], ep[2], ep[3] };
        blk_red<4>(r4b, false, s_scr + 32, tid);
        #pragma unroll
        for (int u = 0; u < 4; u++) {
            float av = ep[u] * frcp(r4b[u]);
            s_att[u * 272 + j] = (u16)cvtpk(av, av);
        }
    }
    __syncthreads();   // B10: att + cn/dv visible

    // ---------- P8: heagg^T = att @ he  (no transpose; he stays row-major) ----------
    // A[m][k] = att[m&3][j]   (rows duplicated mod 4 -> rows of D duplicated, harmless)
    // B[k][n] = he[j][wv*16 + n]
    // D[m][n] = heagg^T[m&3][wv*16+n]; lanes l4==0 hold rows q=0..3 = nh.
    {
        f32x4 hg = {};
        #pragma unroll
        for (int ks = 0; ks < 8; ks++) {
            bf16x8 af = *(const bf16x8*)(&s_att[(l15 & 3) * 272 + ks * 32 + l4 * 8]);
            bf16x8 bh;
            #pragma unroll
            for (int e = 0; e < 8; e++)
                bh[e] = (short)s_A[(ks * 32 + l4 * 8 + e) * 72 + wv * 16 + l15];
            hg = __builtin_amdgcn_mfma_f32_16x16x32_bf16(af, bh, hg, 0, 0, 0);
        }
        if (l4 == 0) {
            f32x4 hv = { hg[0], hg[1], hg[2], hg[3] };
            *(f32x4*)(&s_nin[64 + (wv * 16 + l15) * 4]) = hv;
        }
    }
    if (wv == 0) {
        float a[4] = {};
        #pragma unroll
        for (int e = 0; e < 8; e++) {
            int c = l4 * 8 + e;
            f32x4 w4 = *(const f32x4*)(p.wp1c + c * 64 + 4 * l15);
            float cv = s_cn[c];
            #pragma unroll
            for (int n = 0; n < 4; n++) a[n] += cv * w4[n];
        }
        #pragma unroll
        for (int n = 0; n < 4; n++) {
            a[n] += __shfl_xor(a[n], 16);
            a[n] += __shfl_xor(a[n], 32);
        }
        if (l4 == 0) {
            f32x4 tv;
            #pragma unroll
            for (int n = 0; n < 4; n++) tv[n] = silu(a[n] + p.biasf[B_BP1 + 4 * l15 + n]);
            *(f32x4*)(&s_t1[4 * l15]) = tv;
        }
    } else if (wv == 1) {
        s_nin[lane] = s_rows[128 + lane];
    }
    __syncthreads();   // B11

    // ---------- P9 ----------
    if (wv == 2) {
        float a[4] = {};
        #pragma unroll
        for (int it = 0; it < 16; it++) {
            int k = l4 * 16 + it;
            f32x4 w4 = *(const f32x4*)(p.wp2c + k * 64 + 4 * l15);
            float tk = s_t1[k];
            #pragma unroll
            for (int n = 0; n < 4; n++) a[n] += tk * w4[n];
        }
        #pragma unroll
        for (int n = 0; n < 4; n++) {
            a[n] += __shfl_xor(a[n], 16);
            a[n] += __shfl_xor(a[n], 32);
        }
        if (l4 == 0) {
            f32x4 hv;
            #pragma unroll
            for (int n = 0; n < 4; n++) hv[n] = a[n] + p.biasf[B_BP2 + 4 * l15 + n];
            *(f32x4*)(&s_nin[320 + 4 * l15]) = hv;
        }
        WAVE_FENCE();
    }
    {
        const int Q = (wv == 0) ? 0 : (wv == 1) ? 96 : (wv == 2) ? 288 : 192;
        int k0 = Q + l4 * 24;
        float a[4] = {};
        #pragma unroll
        for (int it = 0; it < 6; it++) {
            f32x4 inv = *(const f32x4*)(&s_nin[k0 + it * 4]);
            #pragma unroll
            for (int r = 0; r < 4; r++) {
                f32x4 w4 = *(const f32x4*)(p.wn1c + (k0 + it * 4 + r) * 64 + 4 * l15);
                #pragma unroll
                for (int n = 0; n < 4; n++) a[n] += inv[r] * w4[n];
            }
        }
        #pragma unroll
        for (int n = 0; n < 4; n++) {
            a[n] += __shfl_xor(a[n], 16);
            a[n] += __shfl_xor(a[n], 32);
        }
        if (l4 == 0) {
            f32x4 pv = { a[0], a[1], a[2], a[3] };
            *(f32x4*)(&s_part[wv * 64 + 4 * l15]) = pv;
        }
    }
    __syncthreads();   // B12

    // ---------- P10 ----------
    if (wv == 0) {
        float v2 = p.biasf[B_BN1 + lane] + (s_part[lane] + s_part[64 + lane])
                 + (s_part[128 + lane] + s_part[192 + lane]);
        s_t1[lane] = silu(v2);
        WAVE_FENCE();
        float a[4] = {};
        #pragma unroll
        for (int it = 0; it < 16; it++) {
            int k = l4 * 16 + it;
            f32x4 w4 = *(const f32x4*)(p.wn2c + k * 64 + 4 * l15);
            float tk = s_t1[k];
            #pragma unroll
            for (int n = 0; n < 4; n++) a[n] += tk * w4[n];
        }
        #pragma unroll
        for (int n = 0; n < 4; n++) {
            a[n] += __shfl_xor(a[n], 16);
            a[n] += __shfl_xor(a[n], 32);
        }
        if (l4 == 0) {
            float o[4];
            #pragma unroll
            for (int n = 0; n < 4; n++) {
                int oo = 4 * l15 + n;
                o[n] = s_rows[128 + oo] + p.biasf[B_BN2 + oo] + a[n];
            }
            if (bf) {
                uint2 w; w.x = cvtpk(o[0], o[1]); w.y = cvtpk(o[2], o[3]);
                *(uint2*)((u16*)p.out + node * 64 + 4 * l15) = w;
            } else {
                f32x4 w = { o[0], o[1], o[2], o[3] };
                *(f32x4*)((float*)p.out + node * 64 + 4 * l15) = w;
            }
        }
    } else if (wv == 1 && lane < 3) {
        int k = lane;
        float vn = s_dv[k] + s_misc[3] * p.vf[node * 3 + k];
        float xn = p.xf[node * 3 + k] + vn;
        STr(p.out, 65536 + node * 3 + k, xn, bf);
        STr(p.out, 68608 + node * 3 + k, vn, bf);
    }
}

extern "C" void kernel_launch(void* const* d_in, const int* in_sizes, int n_in,
                              void* d_out, int out_size, void* d_ws, size_t ws_size,
                              hipStream_t stream) {
    (void)in_sizes; (void)n_in; (void)out_size; (void)ws_size;
    char* ws = (char*)d_ws;

    P p;
    p.h   = d_in[0];  p.x   = d_in[1];  p.v   = d_in[2];
    p.We1 = d_in[3];  p.be1 = d_in[4];  p.We2 = d_in[5];  p.be2 = d_in[6];
    p.Wc1 = d_in[7];  p.bc1 = d_in[8];  p.Wc2 = d_in[9];  p.bc2 = d_in[10];
    p.Wp1 = d_in[11]; p.bp1 = d_in[12]; p.Wp2 = d_in[13]; p.bp2 = d_in[14];
    p.Ws_ = d_in[15]; p.bs_ = d_in[16];
    p.Wn1 = d_in[17]; p.bn1 = d_in[18]; p.Wn2 = d_in[19]; p.bn2 = d_in[20];
    p.Wv1 = d_in[21]; p.bv1 = d_in[22]; p.Wv2 = d_in[23]; p.lg  = d_in[24];
    p.linj  = (float*)(ws + O_LINJ);
    p.lini  = (float*)(ws + O_LINI);
    p.vsc   = (float*)(ws + O_VSC);
    p.wp1c  = (float*)(ws + O_WP1C);
    p.wp2c  = (float*)(ws + O_WP2C);
    p.wn1c  = (float*)(ws + O_WN1C);
    p.wn2c  = (float*)(ws + O_WN2C);
    p.xf    = (float*)(ws + O_XF);
    p.vf    = (float*)(ws + O_VF);
    p.biasf = (float*)(ws + O_BIAS);
    p.we2f  = (u16*)(ws + O_WE2F);
    p.wc1f  = (u16*)(ws + O_WC1F);
    p.wc2f  = (u16*)(ws + O_WC2F);
    p.flagw = (u32*)(ws + O_FLAG);
    p.flag  = (const u32*)(ws + O_FLAG);
    p.out   = d_out;

    hipLaunchKernelGGL(prep_all, dim3(26), dim3(256), 0, stream, p);
    hipLaunchKernelGGL(sake_all, dim3(1024), dim3(256), 0, stream, p);
}